// Round 17
// baseline (377.223 us; speedup 1.0000x reference)
//
#include <hip/hip_runtime.h>
#include <stdint.h>

#define CB 32
#define CT 512
#define CK 256
#define TMID 256
#define SEG 16
#define SHIFT 5.0f
#define ENS 0.006737946999085467f   // e^-5

typedef _Float16 f16x8 __attribute__((ext_vector_type(8)));
typedef float f32x4 __attribute__((ext_vector_type(4)));

__device__ inline uint32_t pk2(float a, float b) {   // exp + pack 2xf16
    return __builtin_bit_cast(uint32_t,
        __builtin_amdgcn_cvt_pkrtz(__expf(a), __expf(b)));
}
__device__ inline uint32_t pkr(float a, float b) {   // pack only
    return __builtin_bit_cast(uint32_t, __builtin_amdgcn_cvt_pkrtz(a, b));
}
__device__ inline void lds_barrier() {
    asm volatile("s_waitcnt lgkmcnt(0)\n\ts_barrier" ::: "memory");
}

// A-frag (E^T tile): lane supplies row c of states [qst+16j .. +16), k-chunk
// kb + kt*32 + g*8. fwd: E[st][k]=exp(trans[k][st]); bwd: exp(trans[st][k]).
#define MKE_F(kt, j) f16x8 E_##kt##_##j; {                                   \
    const float* tp = trans + (size_t)(kb + (kt) * 32 + g * 8) * CK + (qst + 16 * (j) + c); \
    uint4 u_;                                                                \
    u_.x = pk2(tp[0],      tp[CK]);                                          \
    u_.y = pk2(tp[2 * CK], tp[3 * CK]);                                      \
    u_.z = pk2(tp[4 * CK], tp[5 * CK]);                                      \
    u_.w = pk2(tp[6 * CK], tp[7 * CK]);                                      \
    E_##kt##_##j = __builtin_bit_cast(f16x8, u_); }

#define MKE_B(kt, j) f16x8 E_##kt##_##j; {                                   \
    const float* tp = trans + (size_t)(qst + 16 * (j) + c) * CK + (kb + (kt) * 32 + g * 8); \
    uint4 u_;                                                                \
    u_.x = pk2(tp[0], tp[1]);                                                \
    u_.y = pk2(tp[2], tp[3]);                                                \
    u_.z = pk2(tp[4], tp[5]);                                                \
    u_.w = pk2(tp[6], tp[7]);                                                \
    E_##kt##_##j = __builtin_bit_cast(f16x8, u_); }

#define LOADE(MK) \
  MK(0,0) MK(0,1) MK(0,2) MK(0,3)  MK(1,0) MK(1,1) MK(1,2) MK(1,3) \
  MK(2,0) MK(2,1) MK(2,2) MK(2,3)  MK(3,0) MK(3,1) MK(3,2) MK(3,3)

// B-frag read: u_lds row c (512B), XOR-swizzled 16B slots.
#define UREAD(kt) const f16x8 U##kt = *(const f16x8*)(ubr +                  \
    ((c * 512 + kbb + 64 * (kt) + 16 * g) ^ swz));

#define MMQ(kt)                                                              \
    ac0 = __builtin_amdgcn_mfma_f32_16x16x32_f16(E_##kt##_0, U##kt, ac0, 0, 0, 0); \
    ac1 = __builtin_amdgcn_mfma_f32_16x16x32_f16(E_##kt##_1, U##kt, ac1, 0, 0, 0); \
    ac2 = __builtin_amdgcn_mfma_f32_16x16x32_f16(E_##kt##_2, U##kt, ac2, 0, 0, 0); \
    ac3 = __builtin_amdgcn_mfma_f32_16x16x32_f16(E_##kt##_3, U##kt, ac3, 0, 0, 0);

#define MFMA_ALL                                                             \
    UREAD(0) UREAD(1) UREAD(2) UREAD(3)                                      \
    f32x4 ac0 = {0.f,0.f,0.f,0.f}, ac1 = {0.f,0.f,0.f,0.f};                  \
    f32x4 ac2 = {0.f,0.f,0.f,0.f}, ac3 = {0.f,0.f,0.f,0.f};                  \
    MMQ(0) MMQ(1) MMQ(2) MMQ(3)

// Stage 4 f32x4 -> f16 into swizzled u_lds row c.
#define UST(ubw, j, sv) { uint2 v_;                                          \
    v_.x = pkr(sv[0], sv[1]); v_.y = pkr(sv[2], sv[3]);                      \
    *(uint2*)((ubw) + ((c * 512 + 128 * wq + 32 * (j) + 8 * g) ^ swz)) = v_; }

#define MAX16(a, b2, c2, d2)                                                 \
    fmaxf(fmaxf(fmaxf(fmaxf(a[0], a[1]), fmaxf(a[2], a[3])),                 \
                fmaxf(fmaxf(b2[0], b2[1]), fmaxf(b2[2], b2[3]))),            \
          fmaxf(fmaxf(fmaxf(c2[0], c2[1]), fmaxf(c2[2], c2[3])),             \
                fmaxf(fmaxf(d2[0], d2[1]), fmaxf(d2[2], d2[3]))))

#define EXP4(e) {__expf((e).x), __expf((e).y), __expf((e).z), __expf((e).w)}

// 4 blocks x 512 threads (8 waves). Block 0,1: fwd chains 0-15/16-31; 2,3: bwd.
// Wave w: wq = w&3 (state quarter), wh = w>>2 (K half). Lane l: chain c = l&15,
// g = l>>4. 16 chains ride the MFMA N-dim; split-K partials summed via psum.
__global__ __launch_bounds__(512, 1) void crf_main_kernel(
    const float* __restrict__ emissions,    // [B,T,K]
    const int* __restrict__ mask,           // [B,T] (bool -> int32)
    const float* __restrict__ trans,        // [K,K]
    float* __restrict__ ws)
{
    const int tid = threadIdx.x;
    const int w = tid >> 6;
    const int l = tid & 63;
    const int c = l & 15;
    const int g = l >> 4;
    const int wq = w & 3;
    const int wh = w >> 2;
    const int qst = wq * 64;                 // state-quarter base
    const int kb = wh * 128;                 // K-half base (f16 elems)
    const int kbb = kb * 2;                  // bytes
    const int swz = (c & 7) << 4;
    const bool isF = (blockIdx.x < 2);
    const int bbase = (isF ? blockIdx.x : blockIdx.x - 2) * SEG;

    __shared__ __align__(16) _Float16 u_lds[2][SEG * 256];
    __shared__ __align__(16) float psum[4][SEG][68];
    __shared__ __align__(16) float gpt[2][SEG][4];
    __shared__ _Float16 mask_lds[SEG][513];

    for (int idx = tid; idx < SEG * CT; idx += 512) {
        const int cc = idx >> 9, tt = idx & (CT - 1);
        mask_lds[cc][tt] = (_Float16)(mask[(bbase + cc) * CT + tt] ? 1.f : 0.f);
    }

    const float* em0 = emissions + (size_t)(bbase + c) * CT * CK + qst + 4 * g;
    char* const ub0 = (char*)&u_lds[0][0];
    char* const ub1 = (char*)&u_lds[1][0];

    float Mref = SHIFT;
    f32x4 u0, u1, u2, u3;
    float4 ep0, ep1, ep2, ep3;

    if (isF) {
        LOADE(MKE_F)
        if (wh == 0) {
            const float4 e0 = *(const float4*)(em0 + 0);
            const float4 e1 = *(const float4*)(em0 + 16);
            const float4 e2 = *(const float4*)(em0 + 32);
            const float4 e3 = *(const float4*)(em0 + 48);
            u0 = (f32x4){__expf(e0.x-SHIFT), __expf(e0.y-SHIFT), __expf(e0.z-SHIFT), __expf(e0.w-SHIFT)};
            u1 = (f32x4){__expf(e1.x-SHIFT), __expf(e1.y-SHIFT), __expf(e1.z-SHIFT), __expf(e1.w-SHIFT)};
            u2 = (f32x4){__expf(e2.x-SHIFT), __expf(e2.y-SHIFT), __expf(e2.z-SHIFT), __expf(e2.w-SHIFT)};
            u3 = (f32x4){__expf(e3.x-SHIFT), __expf(e3.y-SHIFT), __expf(e3.z-SHIFT), __expf(e3.w-SHIFT)};
            ep0 = *(const float4*)(em0 + CK + 0);
            ep1 = *(const float4*)(em0 + CK + 16);
            ep2 = *(const float4*)(em0 + CK + 32);
            ep3 = *(const float4*)(em0 + CK + 48);
        }
        __syncthreads();

        for (int t = 1; t < TMID; ++t) {
            const int par = t & 1;
            char* const ubp = par ? ub1 : ub0;
            if (wh == 0) {
                float pm = MAX16(u0, u1, u2, u3);
                pm = fmaxf(pm, __shfl_xor(pm, 16, 64));
                pm = fmaxf(pm, __shfl_xor(pm, 32, 64));
                UST(ubp, 0, u0) UST(ubp, 1, u1) UST(ubp, 2, u2) UST(ubp, 3, u3)
                if (l < 16) gpt[par][l][wq] = pm;
            }
            lds_barrier();                       // barrier A

            char* const ubr = ubp;
            MFMA_ALL
            if (wh == 1) {
                *(float4*)&psum[wq][c][ 0 + 4 * g] = make_float4(ac0[0], ac0[1], ac0[2], ac0[3]);
                *(float4*)&psum[wq][c][16 + 4 * g] = make_float4(ac1[0], ac1[1], ac1[2], ac1[3]);
                *(float4*)&psum[wq][c][32 + 4 * g] = make_float4(ac2[0], ac2[1], ac2[2], ac2[3]);
                *(float4*)&psum[wq][c][48 + 4 * g] = make_float4(ac3[0], ac3[1], ac3[2], ac3[3]);
            }
            lds_barrier();                       // barrier B

            if (wh == 0) {
                const float4 gp = *(const float4*)&gpt[par][c][0];
                const float G = fmaxf(fmaxf(gp.x, gp.y), fmaxf(gp.z, gp.w));
                const float fD = __builtin_amdgcn_rcpf(G) * ENS;
                Mref += __logf(G) + SHIFT;
                const f32x4 s0 = ac0 + *(const f32x4*)&psum[wq][c][ 0 + 4 * g];
                const f32x4 s1 = ac1 + *(const f32x4*)&psum[wq][c][16 + 4 * g];
                const f32x4 s2 = ac2 + *(const f32x4*)&psum[wq][c][32 + 4 * g];
                const f32x4 s3 = ac3 + *(const f32x4*)&psum[wq][c][48 + 4 * g];
                const f32x4 ee0 = EXP4(ep0), ee1 = EXP4(ep1);
                const f32x4 ee2 = EXP4(ep2), ee3 = EXP4(ep3);
                const bool mk = ((float)mask_lds[c][t] != 0.f);
                const size_t nt = (size_t)((t + 1 < TMID) ? t + 1 : TMID - 1) * CK;
                ep0 = *(const float4*)(em0 + nt + 0);
                ep1 = *(const float4*)(em0 + nt + 16);
                ep2 = *(const float4*)(em0 + nt + 32);
                ep3 = *(const float4*)(em0 + nt + 48);
                u0 = fD * (mk ? s0 * ee0 : u0);
                u1 = fD * (mk ? s1 * ee1 : u1);
                u2 = fD * (mk ? s2 * ee2 : u2);
                u3 = fD * (mk ? s3 * ee3 : u3);
            }
        }
        if (wh == 0) {
            float* wp = ws + 2 * CB + (size_t)(bbase + c) * CK + qst + 4 * g;
            wp[0]  = Mref + __logf(u0[0]); wp[1]  = Mref + __logf(u0[1]);
            wp[2]  = Mref + __logf(u0[2]); wp[3]  = Mref + __logf(u0[3]);
            wp[16] = Mref + __logf(u1[0]); wp[17] = Mref + __logf(u1[1]);
            wp[18] = Mref + __logf(u1[2]); wp[19] = Mref + __logf(u1[3]);
            wp[32] = Mref + __logf(u2[0]); wp[33] = Mref + __logf(u2[1]);
            wp[34] = Mref + __logf(u2[2]); wp[35] = Mref + __logf(u2[3]);
            wp[48] = Mref + __logf(u3[0]); wp[49] = Mref + __logf(u3[1]);
            wp[50] = Mref + __logf(u3[2]); wp[51] = Mref + __logf(u3[3]);
        }
    } else {
        LOADE(MKE_B)
        if (wh == 0) {
            const float u0i = __expf(-SHIFT);
            u0 = (f32x4){u0i, u0i, u0i, u0i};
            u1 = u0; u2 = u0; u3 = u0;
            const size_t o = (size_t)(CT - 1) * CK;
            ep0 = *(const float4*)(em0 + o + 0);
            ep1 = *(const float4*)(em0 + o + 16);
            ep2 = *(const float4*)(em0 + o + 32);
            ep3 = *(const float4*)(em0 + o + 48);
        }
        __syncthreads();

        for (int tn = CT - 1; tn >= TMID; --tn) {
            const int par = tn & 1;
            char* const ubp = par ? ub1 : ub0;
            if (wh == 0) {
                const f32x4 ee0 = EXP4(ep0), ee1 = EXP4(ep1);
                const f32x4 ee2 = EXP4(ep2), ee3 = EXP4(ep3);
                const f32x4 q0 = u0 * ee0, q1 = u1 * ee1;
                const f32x4 q2 = u2 * ee2, q3 = u3 * ee3;
                float pm = MAX16(q0, q1, q2, q3);
                pm = fmaxf(pm, __shfl_xor(pm, 16, 64));
                pm = fmaxf(pm, __shfl_xor(pm, 32, 64));
                UST(ubp, 0, q0) UST(ubp, 1, q1) UST(ubp, 2, q2) UST(ubp, 3, q3)
                if (l < 16) gpt[par][l][wq] = pm;
            }
            lds_barrier();                       // barrier A

            char* const ubr = ubp;
            MFMA_ALL
            if (wh == 1) {
                *(float4*)&psum[wq][c][ 0 + 4 * g] = make_float4(ac0[0], ac0[1], ac0[2], ac0[3]);
                *(float4*)&psum[wq][c][16 + 4 * g] = make_float4(ac1[0], ac1[1], ac1[2], ac1[3]);
                *(float4*)&psum[wq][c][32 + 4 * g] = make_float4(ac2[0], ac2[1], ac2[2], ac2[3]);
                *(float4*)&psum[wq][c][48 + 4 * g] = make_float4(ac3[0], ac3[1], ac3[2], ac3[3]);
            }
            lds_barrier();                       // barrier B

            if (wh == 0) {
                const float4 gp = *(const float4*)&gpt[par][c][0];
                const float G = fmaxf(fmaxf(gp.x, gp.y), fmaxf(gp.z, gp.w));
                const float fD = __builtin_amdgcn_rcpf(G) * ENS;
                Mref += __logf(G) + SHIFT;
                const f32x4 s0 = ac0 + *(const f32x4*)&psum[wq][c][ 0 + 4 * g];
                const f32x4 s1 = ac1 + *(const f32x4*)&psum[wq][c][16 + 4 * g];
                const f32x4 s2 = ac2 + *(const f32x4*)&psum[wq][c][32 + 4 * g];
                const f32x4 s3 = ac3 + *(const f32x4*)&psum[wq][c][48 + 4 * g];
                const bool mk = ((float)mask_lds[c][tn] != 0.f);
                const size_t nt = (size_t)((tn - 1 > TMID) ? tn - 1 : TMID) * CK;
                ep0 = *(const float4*)(em0 + nt + 0);
                ep1 = *(const float4*)(em0 + nt + 16);
                ep2 = *(const float4*)(em0 + nt + 32);
                ep3 = *(const float4*)(em0 + nt + 48);
                u0 = fD * (mk ? s0 : u0);
                u1 = fD * (mk ? s1 : u1);
                u2 = fD * (mk ? s2 : u2);
                u3 = fD * (mk ? s3 : u3);
            }
        }
        if (wh == 0) {
            float* wp = ws + 2 * CB + CB * CK + (size_t)(bbase + c) * CK + qst + 4 * g;
            wp[0]  = Mref + __logf(u0[0]); wp[1]  = Mref + __logf(u0[1]);
            wp[2]  = Mref + __logf(u0[2]); wp[3]  = Mref + __logf(u0[3]);
            wp[16] = Mref + __logf(u1[0]); wp[17] = Mref + __logf(u1[1]);
            wp[18] = Mref + __logf(u1[2]); wp[19] = Mref + __logf(u1[3]);
            wp[32] = Mref + __logf(u2[0]); wp[33] = Mref + __logf(u2[1]);
            wp[34] = Mref + __logf(u2[2]); wp[35] = Mref + __logf(u2[3]);
            wp[48] = Mref + __logf(u3[0]); wp[49] = Mref + __logf(u3[1]);
            wp[50] = Mref + __logf(u3[2]); wp[51] = Mref + __logf(u3[3]);
        }
    }
}

// Numerator + logZ_b = LSE_j(alpha_mid + beta_mid)
__global__ void crf_combine_kernel(const float* __restrict__ emissions,
                                   const int* __restrict__ tags,
                                   const int* __restrict__ mask,
                                   const float* __restrict__ trans,
                                   float* __restrict__ ws) {
    const int b = blockIdx.x;
    const int tid = threadIdx.x;                 // 256 threads, 4 waves
    const int wid = tid >> 6, lane = tid & 63;
    __shared__ float red[8];
    const float* emB = emissions + (size_t)b * CT * CK;
    const int* tagB = tags + b * CT;
    const int* maskB = mask + b * CT;

    float num = 0.f;
    for (int t = tid; t < CT; t += 256) {
        const float mf = maskB[t] ? 1.f : 0.f;
        num += emB[(size_t)t * CK + tagB[t]] * mf;
        if (t >= 1) num += trans[(size_t)tagB[t - 1] * CK + tagB[t]] * mf;
    }
    #pragma unroll
    for (int off = 32; off > 0; off >>= 1) num += __shfl_down(num, off, 64);
    if (lane == 0) red[wid] = num;
    __syncthreads();
    if (tid == 0) ws[CB + b] = red[0] + red[1] + red[2] + red[3];
    __syncthreads();

    const float v = ws[2 * CB + b * CK + tid] + ws[2 * CB + CB * CK + b * CK + tid];
    float mx = v;
    #pragma unroll
    for (int off = 32; off > 0; off >>= 1) mx = fmaxf(mx, __shfl_down(mx, off, 64));
    mx = __shfl(mx, 0, 64);
    if (lane == 0) red[wid] = mx;
    __syncthreads();
    const float gmx = fmaxf(fmaxf(red[0], red[1]), fmaxf(red[2], red[3]));
    float ex = __expf(v - gmx);
    #pragma unroll
    for (int off = 32; off > 0; off >>= 1) ex += __shfl_down(ex, off, 64);
    if (lane == 0) red[4 + wid] = ex;
    __syncthreads();
    if (tid == 0) ws[b] = gmx + __logf(red[4] + red[5] + red[6] + red[7]);
}

__global__ void crf_finalize_kernel(const float* __restrict__ ws,
                                    float* __restrict__ out) {
    float v = 0.f;
    if ((int)threadIdx.x < CB) v = ws[threadIdx.x] - ws[CB + threadIdx.x];
    #pragma unroll
    for (int off = 32; off > 0; off >>= 1) v += __shfl_down(v, off, 64);
    if (threadIdx.x == 0) out[0] = v * (1.f / CB);
}

extern "C" void kernel_launch(void* const* d_in, const int* in_sizes, int n_in,
                              void* d_out, int out_size, void* d_ws, size_t ws_size,
                              hipStream_t stream) {
    const float* emissions = (const float*)d_in[0];
    const int* tags = (const int*)d_in[1];
    const int* mask = (const int*)d_in[2];
    const float* trans = (const float*)d_in[3];
    float* out = (float*)d_out;
    float* ws = (float*)d_ws;

    crf_main_kernel<<<4, 512, 0, stream>>>(emissions, mask, trans, ws);
    crf_combine_kernel<<<CB, 256, 0, stream>>>(emissions, tags, mask, trans, ws);
    crf_finalize_kernel<<<1, 64, 0, stream>>>(ws, out);
}

// Round 18
// 92.563 us; speedup vs baseline: 4.0753x; 4.0753x over previous
//
#include <hip/hip_runtime.h>
#include <stdint.h>

#define CB 32
#define CT 512
#define CK 256
#define SHIFT 5.0f

typedef _Float16 f16x8 __attribute__((ext_vector_type(8)));
typedef float f32x4 __attribute__((ext_vector_type(4)));

__device__ inline uint32_t pk2(float a, float b) {
    return __builtin_bit_cast(uint32_t,
        __builtin_amdgcn_cvt_pkrtz(__expf(a), __expf(b)));
}

// Barrier draining LDS only; global prefetches stay in flight.
__device__ inline void lds_barrier() {
    asm volatile("s_waitcnt lgkmcnt(0)\n\ts_barrier" ::: "memory");
}

template <int CTRL>
__device__ inline float dpp_maxf(float x) {
    int yi = __builtin_amdgcn_update_dpp(
        __builtin_bit_cast(int, x), __builtin_bit_cast(int, x),
        CTRL, 0xF, 0xF, false);
    return fmaxf(x, __builtin_bit_cast(float, yi));
}

__device__ inline float wave_max(float x) {
    x = dpp_maxf<0x111>(x);
    x = dpp_maxf<0x112>(x);
    x = dpp_maxf<0x114>(x);
    x = dpp_maxf<0x118>(x);
    x = dpp_maxf<0x142>(x);
    x = dpp_maxf<0x143>(x);
    return __builtin_bit_cast(float,
        __builtin_amdgcn_readlane(__builtin_bit_cast(int, x), 63));
}

// FWD B-frag: B[k][col] = exp(trans[k][col]) (strided rows).
#define MKB_F(kt, n) f16x8 B_##kt##_##n; {                                   \
    const float* tp = trans + (size_t)((kt) * 32 + ko8) * CK + (colg + (n) * 16); \
    uint4 u_;                                                                \
    u_.x = pk2(tp[0],      tp[CK]);                                          \
    u_.y = pk2(tp[2 * CK], tp[3 * CK]);                                      \
    u_.z = pk2(tp[4 * CK], tp[5 * CK]);                                      \
    u_.w = pk2(tp[6 * CK], tp[7 * CK]);                                      \
    B_##kt##_##n = __builtin_bit_cast(f16x8, u_); }

// BWD B-frag: B[k][col] = exp(trans[col][k]) (contiguous k).
#define MKB_B(kt, n) f16x8 B_##kt##_##n; {                                   \
    const float* tp = trans + (size_t)(colg + (n) * 16) * CK + ((kt) * 32 + ko8); \
    uint4 u_;                                                                \
    u_.x = pk2(tp[0], tp[1]);                                                \
    u_.y = pk2(tp[2], tp[3]);                                                \
    u_.z = pk2(tp[4], tp[5]);                                                \
    u_.w = pk2(tp[6], tp[7]);                                                \
    B_##kt##_##n = __builtin_bit_cast(f16x8, u_); }

#define LOADB(MK) MK(0,0) MK(0,1) MK(1,0) MK(1,1) MK(2,0) MK(2,1) MK(3,0) MK(3,1) \
                  MK(4,0) MK(4,1) MK(5,0) MK(5,1) MK(6,0) MK(6,1) MK(7,0) MK(7,1)

#define MM(kt)                                                               \
    accA = __builtin_amdgcn_mfma_f32_16x16x32_f16(a##kt##_, B_##kt##_0, accA, 0, 0, 0); \
    accB = __builtin_amdgcn_mfma_f32_16x16x32_f16(a##kt##_, B_##kt##_1, accB, 0, 0, 0);

#define MFMA_STEP(pb)                                                        \
    f16x8 a0_ = *reinterpret_cast<const f16x8*>((pb) + 0   + ko8);           \
    f16x8 a1_ = *reinterpret_cast<const f16x8*>((pb) + 32  + ko8);           \
    f16x8 a2_ = *reinterpret_cast<const f16x8*>((pb) + 64  + ko8);           \
    f16x8 a3_ = *reinterpret_cast<const f16x8*>((pb) + 96  + ko8);           \
    f16x8 a4_ = *reinterpret_cast<const f16x8*>((pb) + 128 + ko8);           \
    f16x8 a5_ = *reinterpret_cast<const f16x8*>((pb) + 160 + ko8);           \
    f16x8 a6_ = *reinterpret_cast<const f16x8*>((pb) + 192 + ko8);           \
    f16x8 a7_ = *reinterpret_cast<const f16x8*>((pb) + 224 + ko8);           \
    f32x4 accA = {0.f, 0.f, 0.f, 0.f};                                       \
    f32x4 accB = {0.f, 0.f, 0.f, 0.f};                                       \
    MM(0) MM(1) MM(2) MM(3) MM(4) MM(5) MM(6) MM(7)

// 4-way segment split via rank-1 factorization of the 128-step segment
// operator. 6 groups of 32 blocks: g0 F-exact[1,128]; g1 F-probe[129,256];
// g2 F-probe[257,384]; g3 B-probe[256,129]; g4 B-probe[384,257];
// g5 B-exact[511,385]. Probes init 0. Step machine = R13 (stale-Mref).
// ws: [0..31] logZ | [32..63] numerator | 64 + g*8192 + b*256 + j : vectors
__global__ __launch_bounds__(512, 1) void crf_seg_kernel(
    const float* __restrict__ emissions,    // [B,T,K]
    const int* __restrict__ mask,           // [B,T] (bool -> int32)
    const float* __restrict__ trans,        // [K,K]
    float* __restrict__ ws)
{
    const int tid = threadIdx.x;
    const int w = tid >> 6;
    const int l = tid & 63;
    const int ko8 = ((l >> 4) & 3) * 8;
    const int colg = w * 32 + (l & 15);
    const int nsel = (l >> 4) & 1;
    const int sj = w * 32 + nsel * 16 + (l & 15);
    const int grp = blockIdx.x >> 5;         // 0..5, block-uniform
    const int b = blockIdx.x & 31;

    __shared__ __align__(16) _Float16 pbuf[2][CK];
    __shared__ __align__(16) float wmaxl[2][8];
    __shared__ float mask_lds[CT];

    const float* emB = emissions + (size_t)b * CT * CK;
    const int* maskB = mask + b * CT;
    mask_lds[tid] = maskB[tid] ? 1.f : 0.f;

    float* const outp = ws + 64 + (size_t)grp * CB * CK + (size_t)b * CK;

    if (grp < 3) {
        // ======================= FORWARD =======================
        const int t_lo = (grp == 0) ? 1 : (grp == 1) ? 129 : 257;
        const int t_hi = t_lo + 127;
        LOADB(MKB_F)

        float aj = (grp == 0) ? emB[sj] : 0.f;
        float emit_next = emB[(size_t)t_lo * CK + sj];

        {   // prologue: exact Mref
            const float mw = wave_max(aj);
            if (l == 0) wmaxl[0][w] = mw;
        }
        __syncthreads();
        float Mref;
        {
            const float4 wa = *reinterpret_cast<const float4*>(&wmaxl[0][0]);
            const float4 wb = *reinterpret_cast<const float4*>(&wmaxl[0][4]);
            Mref = fmaxf(fmaxf(fmaxf(wa.x, wa.y), fmaxf(wa.z, wa.w)),
                         fmaxf(fmaxf(wb.x, wb.y), fmaxf(wb.z, wb.w))) + SHIFT;
        }
        __syncthreads();

        for (int t = t_lo; t <= t_hi; ++t) {
            const float emit_t = emit_next;
            const int nxt = (t + 1 <= t_hi) ? (t + 1) : t_hi;
            emit_next = emB[(size_t)nxt * CK + sj];
            const int bsel = t & 1;

            const float mw = wave_max(aj);
            if (l == 0) wmaxl[bsel][w] = mw;
            const float pv = __expf(aj - Mref);
            if (l < 32) pbuf[bsel][w * 32 + l] = (_Float16)pv;
            lds_barrier();

            const float4 wa = *reinterpret_cast<const float4*>(&wmaxl[bsel][0]);
            const float4 wb = *reinterpret_cast<const float4*>(&wmaxl[bsel][4]);
            const float Mnext = fmaxf(fmaxf(fmaxf(wa.x, wa.y), fmaxf(wa.z, wa.w)),
                                      fmaxf(fmaxf(wb.x, wb.y), fmaxf(wb.z, wb.w))) + SHIFT;

            MFMA_STEP(pbuf[bsel])
            const float s = nsel ? accB[0] : accA[0];
            const float anew = Mref + __logf(s) + emit_t;
            aj = (mask_lds[t] != 0.f) ? anew : aj;
            Mref = Mnext;
        }
        if (l < 32) outp[w * 32 + l] = aj;
    } else {
        // ======================= BACKWARD =======================
        const int tn_hi = (grp == 3) ? 256 : (grp == 4) ? 384 : 511;
        const int tn_lo = (grp == 3) ? 129 : (grp == 4) ? 257 : 385;
        LOADB(MKB_B)

        float bj = 0.f;
        float emit_next = emB[(size_t)tn_hi * CK + sj];
        __syncthreads();   // mask_lds ready

        {   // prologue: exact Mref over v = bj + emit[tn_hi]
            const float mw = wave_max(bj + emit_next);
            if (l == 0) wmaxl[0][w] = mw;
        }
        __syncthreads();
        float Mref;
        {
            const float4 wa = *reinterpret_cast<const float4*>(&wmaxl[0][0]);
            const float4 wb = *reinterpret_cast<const float4*>(&wmaxl[0][4]);
            Mref = fmaxf(fmaxf(fmaxf(wa.x, wa.y), fmaxf(wa.z, wa.w)),
                         fmaxf(fmaxf(wb.x, wb.y), fmaxf(wb.z, wb.w))) + SHIFT;
        }
        __syncthreads();

        for (int tn = tn_hi; tn >= tn_lo; --tn) {
            const float emit_t = emit_next;
            const int nxt = (tn - 1 > tn_lo) ? (tn - 1) : tn_lo;
            emit_next = emB[(size_t)nxt * CK + sj];
            const int bsel = tn & 1;

            const float v = bj + emit_t;
            const float mw = wave_max(v);
            if (l == 0) wmaxl[bsel][w] = mw;
            const float pv = __expf(v - Mref);
            if (l < 32) pbuf[bsel][w * 32 + l] = (_Float16)pv;
            lds_barrier();

            const float4 wa = *reinterpret_cast<const float4*>(&wmaxl[bsel][0]);
            const float4 wb = *reinterpret_cast<const float4*>(&wmaxl[bsel][4]);
            const float Mnext = fmaxf(fmaxf(fmaxf(wa.x, wa.y), fmaxf(wa.z, wa.w)),
                                      fmaxf(fmaxf(wb.x, wb.y), fmaxf(wb.z, wb.w))) + SHIFT;

            MFMA_STEP(pbuf[bsel])
            const float s = nsel ? accB[0] : accA[0];
            const float bnew = Mref + __logf(s);
            bj = (mask_lds[tn] != 0.f) ? bnew : bj;
            Mref = Mnext;
        }
        if (l < 32) outp[w * 32 + l] = bj;
    }
}

__device__ inline float block_lse(float v, float* red, int tid) {
    const int wid = tid >> 6, lane = tid & 63;
    float mx = v;
    #pragma unroll
    for (int off = 32; off > 0; off >>= 1) mx = fmaxf(mx, __shfl_down(mx, off, 64));
    mx = __shfl(mx, 0, 64);
    if (lane == 0) red[wid] = mx;
    __syncthreads();
    const float g = fmaxf(fmaxf(red[0], red[1]), fmaxf(red[2], red[3]));
    float ex = __expf(v - g);
    #pragma unroll
    for (int off = 32; off > 0; off >>= 1) ex += __shfl_down(ex, off, 64);
    if (lane == 0) red[4 + wid] = ex;
    __syncthreads();
    const float r = g + __logf(red[4] + red[5] + red[6] + red[7]);
    __syncthreads();
    return r;
}

// Numerator + logZ_b = LSE(A+q2) + LSE(p2+q3) + LSE(p3+B) - LSE(p2) - LSE(p3)
__global__ void crf_combine_kernel(const float* __restrict__ emissions,
                                   const int* __restrict__ tags,
                                   const int* __restrict__ mask,
                                   const float* __restrict__ trans,
                                   float* __restrict__ ws) {
    const int b = blockIdx.x;
    const int tid = threadIdx.x;                 // 256 threads
    const int wid = tid >> 6, lane = tid & 63;
    __shared__ float red[8];
    const float* emB = emissions + (size_t)b * CT * CK;
    const int* tagB = tags + b * CT;
    const int* maskB = mask + b * CT;

    float num = 0.f;
    for (int t = tid; t < CT; t += 256) {
        const float mf = maskB[t] ? 1.f : 0.f;
        num += emB[(size_t)t * CK + tagB[t]] * mf;
        if (t >= 1) num += trans[(size_t)tagB[t - 1] * CK + tagB[t]] * mf;
    }
    #pragma unroll
    for (int off = 32; off > 0; off >>= 1) num += __shfl_down(num, off, 64);
    if (lane == 0) red[wid] = num;
    __syncthreads();
    if (tid == 0) ws[CB + b] = red[0] + red[1] + red[2] + red[3];
    __syncthreads();

    const float* base = ws + 64;
    const float A  = base[0 * CB * CK + b * CK + tid];
    const float p2 = base[1 * CB * CK + b * CK + tid];
    const float p3 = base[2 * CB * CK + b * CK + tid];
    const float q2 = base[3 * CB * CK + b * CK + tid];
    const float q3 = base[4 * CB * CK + b * CK + tid];
    const float Bv = base[5 * CB * CK + b * CK + tid];

    const float r0 = block_lse(A + q2, red, tid);
    const float r1 = block_lse(p2 + q3, red, tid);
    const float r2 = block_lse(p3 + Bv, red, tid);
    const float n1 = block_lse(p2, red, tid);
    const float n2 = block_lse(p3, red, tid);
    if (tid == 0) ws[b] = r0 + r1 + r2 - n1 - n2;
}

__global__ void crf_finalize_kernel(const float* __restrict__ ws,
                                    float* __restrict__ out) {
    float v = 0.f;
    if ((int)threadIdx.x < CB) v = ws[threadIdx.x] - ws[CB + threadIdx.x];
    #pragma unroll
    for (int off = 32; off > 0; off >>= 1) v += __shfl_down(v, off, 64);
    if (threadIdx.x == 0) out[0] = v * (1.f / CB);
}

extern "C" void kernel_launch(void* const* d_in, const int* in_sizes, int n_in,
                              void* d_out, int out_size, void* d_ws, size_t ws_size,
                              hipStream_t stream) {
    const float* emissions = (const float*)d_in[0];
    const int* tags = (const int*)d_in[1];
    const int* mask = (const int*)d_in[2];
    const float* trans = (const float*)d_in[3];
    float* out = (float*)d_out;
    float* ws = (float*)d_ws;

    crf_seg_kernel<<<6 * CB, 512, 0, stream>>>(emissions, mask, trans, ws);
    crf_combine_kernel<<<CB, 256, 0, stream>>>(emissions, tags, mask, trans, ws);
    crf_finalize_kernel<<<1, 64, 0, stream>>>(ws, out);
}

// Round 19
// 90.209 us; speedup vs baseline: 4.1817x; 1.0261x over previous
//
#include <hip/hip_runtime.h>
#include <stdint.h>

#define CB 32
#define CT 512
#define CK 256
#define SHIFT 5.0f

typedef _Float16 f16x8 __attribute__((ext_vector_type(8)));
typedef float f32x4 __attribute__((ext_vector_type(4)));

__device__ inline uint32_t pk2(float a, float b) {
    return __builtin_bit_cast(uint32_t,
        __builtin_amdgcn_cvt_pkrtz(__expf(a), __expf(b)));
}

// Barrier draining LDS only; global prefetches stay in flight.
__device__ inline void lds_barrier() {
    asm volatile("s_waitcnt lgkmcnt(0)\n\ts_barrier" ::: "memory");
}

template <int CTRL>
__device__ inline float dpp_maxf(float x) {
    int yi = __builtin_amdgcn_update_dpp(
        __builtin_bit_cast(int, x), __builtin_bit_cast(int, x),
        CTRL, 0xF, 0xF, false);
    return fmaxf(x, __builtin_bit_cast(float, yi));
}

__device__ inline float wave_max(float x) {
    x = dpp_maxf<0x111>(x);
    x = dpp_maxf<0x112>(x);
    x = dpp_maxf<0x114>(x);
    x = dpp_maxf<0x118>(x);
    x = dpp_maxf<0x142>(x);
    x = dpp_maxf<0x143>(x);
    return __builtin_bit_cast(float,
        __builtin_amdgcn_readlane(__builtin_bit_cast(int, x), 63));
}

// FWD B-frag: B[k][col] = exp(trans[k][col]) (strided rows).
#define MKB_F(kt, n) f16x8 B_##kt##_##n; {                                   \
    const float* tp = trans + (size_t)((kt) * 32 + ko8) * CK + (colg + (n) * 16); \
    uint4 u_;                                                                \
    u_.x = pk2(tp[0],      tp[CK]);                                          \
    u_.y = pk2(tp[2 * CK], tp[3 * CK]);                                      \
    u_.z = pk2(tp[4 * CK], tp[5 * CK]);                                      \
    u_.w = pk2(tp[6 * CK], tp[7 * CK]);                                      \
    B_##kt##_##n = __builtin_bit_cast(f16x8, u_); }

// BWD B-frag: B[k][col] = exp(trans[col][k]) (contiguous k).
#define MKB_B(kt, n) f16x8 B_##kt##_##n; {                                   \
    const float* tp = trans + (size_t)(colg + (n) * 16) * CK + ((kt) * 32 + ko8); \
    uint4 u_;                                                                \
    u_.x = pk2(tp[0], tp[1]);                                                \
    u_.y = pk2(tp[2], tp[3]);                                                \
    u_.z = pk2(tp[4], tp[5]);                                                \
    u_.w = pk2(tp[6], tp[7]);                                                \
    B_##kt##_##n = __builtin_bit_cast(f16x8, u_); }

#define LOADB(MK) MK(0,0) MK(0,1) MK(1,0) MK(1,1) MK(2,0) MK(2,1) MK(3,0) MK(3,1) \
                  MK(4,0) MK(4,1) MK(5,0) MK(5,1) MK(6,0) MK(6,1) MK(7,0) MK(7,1)

#define MM(kt)                                                               \
    accA = __builtin_amdgcn_mfma_f32_16x16x32_f16(a##kt##_, B_##kt##_0, accA, 0, 0, 0); \
    accB = __builtin_amdgcn_mfma_f32_16x16x32_f16(a##kt##_, B_##kt##_1, accB, 0, 0, 0);

#define MFMA_STEP(pb)                                                        \
    f16x8 a0_ = *reinterpret_cast<const f16x8*>((pb) + 0   + ko8);           \
    f16x8 a1_ = *reinterpret_cast<const f16x8*>((pb) + 32  + ko8);           \
    f16x8 a2_ = *reinterpret_cast<const f16x8*>((pb) + 64  + ko8);           \
    f16x8 a3_ = *reinterpret_cast<const f16x8*>((pb) + 96  + ko8);           \
    f16x8 a4_ = *reinterpret_cast<const f16x8*>((pb) + 128 + ko8);           \
    f16x8 a5_ = *reinterpret_cast<const f16x8*>((pb) + 160 + ko8);           \
    f16x8 a6_ = *reinterpret_cast<const f16x8*>((pb) + 192 + ko8);           \
    f16x8 a7_ = *reinterpret_cast<const f16x8*>((pb) + 224 + ko8);           \
    f32x4 accA = {0.f, 0.f, 0.f, 0.f};                                       \
    f32x4 accB = {0.f, 0.f, 0.f, 0.f};                                       \
    MM(0) MM(1) MM(2) MM(3) MM(4) MM(5) MM(6) MM(7)

// 8-way segment split (rank-1 factorization at 7 boundaries 64..448).
// 14 groups x 32 chains = 448 blocks, depth 64:
//   grp 0..6  : FWD, t in [64*grp+1, 64*(grp+1)], init = (grp==0) ? em[0] : 0
//               -> fa[grp] = alpha-like at boundary 64*(grp+1)
//   grp 7..13 : BWD, j = grp-7; probes j=0..5: tn in [64j+128, 64j+65];
//               exact j=6: tn in [511, 449]; init 0
//               -> fb[j] = beta-like at boundary 64*(j+1)
// ws: [0..31] logZ | [32..63] numerator | 64 + slot*8192 + b*256 + j
__global__ __launch_bounds__(512, 4) void crf_seg_kernel(
    const float* __restrict__ emissions,    // [B,T,K]
    const int* __restrict__ mask,           // [B,T] (bool -> int32)
    const float* __restrict__ trans,        // [K,K]
    float* __restrict__ ws)
{
    const int tid = threadIdx.x;
    const int w = tid >> 6;
    const int l = tid & 63;
    const int ko8 = ((l >> 4) & 3) * 8;
    const int colg = w * 32 + (l & 15);
    const int nsel = (l >> 4) & 1;
    const int sj = w * 32 + nsel * 16 + (l & 15);
    const int grp = blockIdx.x >> 5;         // 0..13, block-uniform
    const int b = blockIdx.x & 31;

    __shared__ __align__(16) _Float16 pbuf[2][CK];
    __shared__ __align__(16) float wmaxl[2][8];
    __shared__ float mask_lds[CT];

    const float* emB = emissions + (size_t)b * CT * CK;
    const int* maskB = mask + b * CT;
    mask_lds[tid] = maskB[tid] ? 1.f : 0.f;

    float* const outp = ws + 64 + (size_t)grp * CB * CK + (size_t)b * CK;

    if (grp < 7) {
        // ======================= FORWARD =======================
        const int t_lo = 64 * grp + 1;
        const int t_hi = 64 * (grp + 1);
        LOADB(MKB_F)

        float aj = (grp == 0) ? emB[sj] : 0.f;
        float emit_next = emB[(size_t)t_lo * CK + sj];

        {   // prologue: exact Mref
            const float mw = wave_max(aj);
            if (l == 0) wmaxl[0][w] = mw;
        }
        __syncthreads();
        float Mref;
        {
            const float4 wa = *reinterpret_cast<const float4*>(&wmaxl[0][0]);
            const float4 wb = *reinterpret_cast<const float4*>(&wmaxl[0][4]);
            Mref = fmaxf(fmaxf(fmaxf(wa.x, wa.y), fmaxf(wa.z, wa.w)),
                         fmaxf(fmaxf(wb.x, wb.y), fmaxf(wb.z, wb.w))) + SHIFT;
        }
        __syncthreads();

        for (int t = t_lo; t <= t_hi; ++t) {
            const float emit_t = emit_next;
            const int nxt = (t + 1 <= t_hi) ? (t + 1) : t_hi;
            emit_next = emB[(size_t)nxt * CK + sj];
            const int bsel = t & 1;

            const float mw = wave_max(aj);
            if (l == 0) wmaxl[bsel][w] = mw;
            const float pv = __expf(aj - Mref);
            if (l < 32) pbuf[bsel][w * 32 + l] = (_Float16)pv;
            lds_barrier();

            const float4 wa = *reinterpret_cast<const float4*>(&wmaxl[bsel][0]);
            const float4 wb = *reinterpret_cast<const float4*>(&wmaxl[bsel][4]);
            const float Mnext = fmaxf(fmaxf(fmaxf(wa.x, wa.y), fmaxf(wa.z, wa.w)),
                                      fmaxf(fmaxf(wb.x, wb.y), fmaxf(wb.z, wb.w))) + SHIFT;

            MFMA_STEP(pbuf[bsel])
            const float s = nsel ? accB[0] : accA[0];
            const float anew = Mref + __logf(s) + emit_t;
            aj = (mask_lds[t] != 0.f) ? anew : aj;
            Mref = Mnext;
        }
        if (l < 32) outp[w * 32 + l] = aj;
    } else {
        // ======================= BACKWARD =======================
        const int j = grp - 7;               // 0..6
        const int tn_hi = (j == 6) ? 511 : 64 * j + 128;
        const int tn_lo = (j == 6) ? 449 : 64 * j + 65;
        LOADB(MKB_B)

        float bj = 0.f;
        float emit_next = emB[(size_t)tn_hi * CK + sj];
        __syncthreads();   // mask_lds ready

        {   // prologue: exact Mref over v = bj + emit[tn_hi]
            const float mw = wave_max(bj + emit_next);
            if (l == 0) wmaxl[0][w] = mw;
        }
        __syncthreads();
        float Mref;
        {
            const float4 wa = *reinterpret_cast<const float4*>(&wmaxl[0][0]);
            const float4 wb = *reinterpret_cast<const float4*>(&wmaxl[0][4]);
            Mref = fmaxf(fmaxf(fmaxf(wa.x, wa.y), fmaxf(wa.z, wa.w)),
                         fmaxf(fmaxf(wb.x, wb.y), fmaxf(wb.z, wb.w))) + SHIFT;
        }
        __syncthreads();

        for (int tn = tn_hi; tn >= tn_lo; --tn) {
            const float emit_t = emit_next;
            const int nxt = (tn - 1 > tn_lo) ? (tn - 1) : tn_lo;
            emit_next = emB[(size_t)nxt * CK + sj];
            const int bsel = tn & 1;

            const float v = bj + emit_t;
            const float mw = wave_max(v);
            if (l == 0) wmaxl[bsel][w] = mw;
            const float pv = __expf(v - Mref);
            if (l < 32) pbuf[bsel][w * 32 + l] = (_Float16)pv;
            lds_barrier();

            const float4 wa = *reinterpret_cast<const float4*>(&wmaxl[bsel][0]);
            const float4 wb = *reinterpret_cast<const float4*>(&wmaxl[bsel][4]);
            const float Mnext = fmaxf(fmaxf(fmaxf(wa.x, wa.y), fmaxf(wa.z, wa.w)),
                                      fmaxf(fmaxf(wb.x, wb.y), fmaxf(wb.z, wb.w))) + SHIFT;

            MFMA_STEP(pbuf[bsel])
            const float s = nsel ? accB[0] : accA[0];
            const float bnew = Mref + __logf(s);
            bj = (mask_lds[tn] != 0.f) ? bnew : bj;
            Mref = Mnext;
        }
        if (l < 32) outp[w * 32 + l] = bj;
    }
}

__device__ inline float block_lse(float v, float* red, int tid) {
    const int wid = tid >> 6, lane = tid & 63;
    float mx = v;
    #pragma unroll
    for (int off = 32; off > 0; off >>= 1) mx = fmaxf(mx, __shfl_down(mx, off, 64));
    mx = __shfl(mx, 0, 64);
    if (lane == 0) red[wid] = mx;
    __syncthreads();
    const float g = fmaxf(fmaxf(red[0], red[1]), fmaxf(red[2], red[3]));
    float ex = __expf(v - g);
    #pragma unroll
    for (int off = 32; off > 0; off >>= 1) ex += __shfl_down(ex, off, 64);
    if (lane == 0) red[4 + wid] = ex;
    __syncthreads();
    const float r = g + __logf(red[4] + red[5] + red[6] + red[7]);
    __syncthreads();
    return r;
}

// Numerator + telescoped logZ:
// logZ = LSE(fa0+fb0) + sum_{k=1..6} [LSE(fa_k+fb_k) - LSE(fa_k)]
__global__ void crf_combine_kernel(const float* __restrict__ emissions,
                                   const int* __restrict__ tags,
                                   const int* __restrict__ mask,
                                   const float* __restrict__ trans,
                                   float* __restrict__ ws) {
    const int b = blockIdx.x;
    const int tid = threadIdx.x;                 // 256 threads
    const int wid = tid >> 6, lane = tid & 63;
    __shared__ float red[8];
    const float* emB = emissions + (size_t)b * CT * CK;
    const int* tagB = tags + b * CT;
    const int* maskB = mask + b * CT;

    float num = 0.f;
    for (int t = tid; t < CT; t += 256) {
        const float mf = maskB[t] ? 1.f : 0.f;
        num += emB[(size_t)t * CK + tagB[t]] * mf;
        if (t >= 1) num += trans[(size_t)tagB[t - 1] * CK + tagB[t]] * mf;
    }
    #pragma unroll
    for (int off = 32; off > 0; off >>= 1) num += __shfl_down(num, off, 64);
    if (lane == 0) red[wid] = num;
    __syncthreads();
    if (tid == 0) ws[CB + b] = red[0] + red[1] + red[2] + red[3];
    __syncthreads();

    const float* base = ws + 64;
    float r;
    {
        const float fa0 = base[0 * CB * CK + b * CK + tid];
        const float fb0 = base[7 * CB * CK + b * CK + tid];
        r = block_lse(fa0 + fb0, red, tid);
    }
    #pragma unroll
    for (int k = 1; k <= 6; ++k) {
        const float fa = base[(size_t)k * CB * CK + b * CK + tid];
        const float fb = base[(size_t)(7 + k) * CB * CK + b * CK + tid];
        r += block_lse(fa + fb, red, tid);
        r -= block_lse(fa, red, tid);
    }
    if (tid == 0) ws[b] = r;
}

__global__ void crf_finalize_kernel(const float* __restrict__ ws,
                                    float* __restrict__ out) {
    float v = 0.f;
    if ((int)threadIdx.x < CB) v = ws[threadIdx.x] - ws[CB + threadIdx.x];
    #pragma unroll
    for (int off = 32; off > 0; off >>= 1) v += __shfl_down(v, off, 64);
    if (threadIdx.x == 0) out[0] = v * (1.f / CB);
}

extern "C" void kernel_launch(void* const* d_in, const int* in_sizes, int n_in,
                              void* d_out, int out_size, void* d_ws, size_t ws_size,
                              hipStream_t stream) {
    const float* emissions = (const float*)d_in[0];
    const int* tags = (const int*)d_in[1];
    const int* mask = (const int*)d_in[2];
    const float* trans = (const float*)d_in[3];
    float* out = (float*)d_out;
    float* ws = (float*)d_ws;

    crf_seg_kernel<<<14 * CB, 512, 0, stream>>>(emissions, mask, trans, ws);
    crf_combine_kernel<<<CB, 256, 0, stream>>>(emissions, tags, mask, trans, ws);
    crf_finalize_kernel<<<1, 64, 0, stream>>>(ws, out);
}

// Round 20
// 76.281 us; speedup vs baseline: 4.9452x; 1.1826x over previous
//
#include <hip/hip_runtime.h>
#include <stdint.h>

#define CB 32
#define CT 512
#define CK 256
#define SHIFT 5.0f

typedef _Float16 f16x8 __attribute__((ext_vector_type(8)));
typedef float f32x4 __attribute__((ext_vector_type(4)));

__device__ inline uint32_t pk2(float a, float b) {
    return __builtin_bit_cast(uint32_t,
        __builtin_amdgcn_cvt_pkrtz(__expf(a), __expf(b)));
}

// Barrier draining LDS only; global prefetches stay in flight.
__device__ inline void lds_barrier() {
    asm volatile("s_waitcnt lgkmcnt(0)\n\ts_barrier" ::: "memory");
}

template <int CTRL>
__device__ inline float dpp_maxf(float x) {
    int yi = __builtin_amdgcn_update_dpp(
        __builtin_bit_cast(int, x), __builtin_bit_cast(int, x),
        CTRL, 0xF, 0xF, false);
    return fmaxf(x, __builtin_bit_cast(float, yi));
}

__device__ inline float wave_max(float x) {
    x = dpp_maxf<0x111>(x);
    x = dpp_maxf<0x112>(x);
    x = dpp_maxf<0x114>(x);
    x = dpp_maxf<0x118>(x);
    x = dpp_maxf<0x142>(x);
    x = dpp_maxf<0x143>(x);
    return __builtin_bit_cast(float,
        __builtin_amdgcn_readlane(__builtin_bit_cast(int, x), 63));
}

// FWD B-frag: B[k][col] = exp(trans[k][col]) (strided rows).
#define MKB_F(kt, n) f16x8 B_##kt##_##n; {                                   \
    const float* tp = trans + (size_t)((kt) * 32 + ko8) * CK + (colg + (n) * 16); \
    uint4 u_;                                                                \
    u_.x = pk2(tp[0],      tp[CK]);                                          \
    u_.y = pk2(tp[2 * CK], tp[3 * CK]);                                      \
    u_.z = pk2(tp[4 * CK], tp[5 * CK]);                                      \
    u_.w = pk2(tp[6 * CK], tp[7 * CK]);                                      \
    B_##kt##_##n = __builtin_bit_cast(f16x8, u_); }

// BWD B-frag: B[k][col] = exp(trans[col][k]) (contiguous k).
#define MKB_B(kt, n) f16x8 B_##kt##_##n; {                                   \
    const float* tp = trans + (size_t)(colg + (n) * 16) * CK + ((kt) * 32 + ko8); \
    uint4 u_;                                                                \
    u_.x = pk2(tp[0], tp[1]);                                                \
    u_.y = pk2(tp[2], tp[3]);                                                \
    u_.z = pk2(tp[4], tp[5]);                                                \
    u_.w = pk2(tp[6], tp[7]);                                                \
    B_##kt##_##n = __builtin_bit_cast(f16x8, u_); }

#define LOADB(MK) MK(0,0) MK(0,1) MK(1,0) MK(1,1) MK(2,0) MK(2,1) MK(3,0) MK(3,1) \
                  MK(4,0) MK(4,1) MK(5,0) MK(5,1) MK(6,0) MK(6,1) MK(7,0) MK(7,1)

#define MM(kt)                                                               \
    accA = __builtin_amdgcn_mfma_f32_16x16x32_f16(a##kt##_, B_##kt##_0, accA, 0, 0, 0); \
    accB = __builtin_amdgcn_mfma_f32_16x16x32_f16(a##kt##_, B_##kt##_1, accB, 0, 0, 0);

#define MFMA_STEP(pb)                                                        \
    f16x8 a0_ = *reinterpret_cast<const f16x8*>((pb) + 0   + ko8);           \
    f16x8 a1_ = *reinterpret_cast<const f16x8*>((pb) + 32  + ko8);           \
    f16x8 a2_ = *reinterpret_cast<const f16x8*>((pb) + 64  + ko8);           \
    f16x8 a3_ = *reinterpret_cast<const f16x8*>((pb) + 96  + ko8);           \
    f16x8 a4_ = *reinterpret_cast<const f16x8*>((pb) + 128 + ko8);           \
    f16x8 a5_ = *reinterpret_cast<const f16x8*>((pb) + 160 + ko8);           \
    f16x8 a6_ = *reinterpret_cast<const f16x8*>((pb) + 192 + ko8);           \
    f16x8 a7_ = *reinterpret_cast<const f16x8*>((pb) + 224 + ko8);           \
    f32x4 accA = {0.f, 0.f, 0.f, 0.f};                                       \
    f32x4 accB = {0.f, 0.f, 0.f, 0.f};                                       \
    MM(0) MM(1) MM(2) MM(3) MM(4) MM(5) MM(6) MM(7)

// Full fwd run over t in [T_LO, T_HI], alpha init AJ_INIT, result -> OUTP.
#define FWD_RUN(T_LO, T_HI, AJ_INIT, OUTP) {                                 \
    LOADB(MKB_F)                                                             \
    float aj = (AJ_INIT);                                                    \
    float emit_next = emB[(size_t)(T_LO) * CK + sj];                         \
    {   const float mw = wave_max(aj);                                       \
        if (l == 0) wmaxl[0][w] = mw; }                                      \
    __syncthreads();                                                         \
    float Mref;                                                              \
    {   const float4 wa = *reinterpret_cast<const float4*>(&wmaxl[0][0]);    \
        const float4 wb = *reinterpret_cast<const float4*>(&wmaxl[0][4]);    \
        Mref = fmaxf(fmaxf(fmaxf(wa.x, wa.y), fmaxf(wa.z, wa.w)),            \
                     fmaxf(fmaxf(wb.x, wb.y), fmaxf(wb.z, wb.w))) + SHIFT; } \
    __syncthreads();                                                         \
    for (int t = (T_LO); t <= (T_HI); ++t) {                                 \
        const float emit_t = emit_next;                                      \
        const int nxt = (t + 1 <= (T_HI)) ? (t + 1) : (T_HI);                \
        emit_next = emB[(size_t)nxt * CK + sj];                              \
        const int bsel = t & 1;                                              \
        const float mw = wave_max(aj);                                       \
        if (l == 0) wmaxl[bsel][w] = mw;                                     \
        const float pv = __expf(aj - Mref);                                  \
        if (l < 32) pbuf[bsel][w * 32 + l] = (_Float16)pv;                   \
        lds_barrier();                                                       \
        const float4 wa = *reinterpret_cast<const float4*>(&wmaxl[bsel][0]); \
        const float4 wb = *reinterpret_cast<const float4*>(&wmaxl[bsel][4]); \
        const float Mnext = fmaxf(fmaxf(fmaxf(wa.x, wa.y), fmaxf(wa.z, wa.w)), \
                                  fmaxf(fmaxf(wb.x, wb.y), fmaxf(wb.z, wb.w))) + SHIFT; \
        MFMA_STEP(pbuf[bsel])                                                \
        const float s = nsel ? accB[0] : accA[0];                            \
        const float anew = Mref + __logf(s) + emit_t;                        \
        aj = (mask_lds[t] != 0.f) ? anew : aj;                               \
        Mref = Mnext;                                                        \
    }                                                                        \
    if (l < 32) (OUTP)[w * 32 + l] = aj; }

// Full bwd run over tn in [TN_HI down to TN_LO], 0-init, result -> OUTP.
#define BWD_RUN(TN_LO, TN_HI, OUTP) {                                        \
    LOADB(MKB_B)                                                             \
    float bj = 0.f;                                                          \
    float emit_next = emB[(size_t)(TN_HI) * CK + sj];                        \
    __syncthreads();                                                         \
    {   const float mw = wave_max(bj + emit_next);                           \
        if (l == 0) wmaxl[0][w] = mw; }                                      \
    __syncthreads();                                                         \
    float Mref;                                                              \
    {   const float4 wa = *reinterpret_cast<const float4*>(&wmaxl[0][0]);    \
        const float4 wb = *reinterpret_cast<const float4*>(&wmaxl[0][4]);    \
        Mref = fmaxf(fmaxf(fmaxf(wa.x, wa.y), fmaxf(wa.z, wa.w)),            \
                     fmaxf(fmaxf(wb.x, wb.y), fmaxf(wb.z, wb.w))) + SHIFT; } \
    __syncthreads();                                                         \
    for (int tn = (TN_HI); tn >= (TN_LO); --tn) {                            \
        const float emit_t = emit_next;                                      \
        const int nxt = (tn - 1 > (TN_LO)) ? (tn - 1) : (TN_LO);             \
        emit_next = emB[(size_t)nxt * CK + sj];                              \
        const int bsel = tn & 1;                                             \
        const float v = bj + emit_t;                                         \
        const float mw = wave_max(v);                                        \
        if (l == 0) wmaxl[bsel][w] = mw;                                     \
        const float pv = __expf(v - Mref);                                   \
        if (l < 32) pbuf[bsel][w * 32 + l] = (_Float16)pv;                   \
        lds_barrier();                                                       \
        const float4 wa = *reinterpret_cast<const float4*>(&wmaxl[bsel][0]); \
        const float4 wb = *reinterpret_cast<const float4*>(&wmaxl[bsel][4]); \
        const float Mnext = fmaxf(fmaxf(fmaxf(wa.x, wa.y), fmaxf(wa.z, wa.w)), \
                                  fmaxf(fmaxf(wb.x, wb.y), fmaxf(wb.z, wb.w))) + SHIFT; \
        MFMA_STEP(pbuf[bsel])                                                \
        const float s = nsel ? accB[0] : accA[0];                            \
        const float bnew = Mref + __logf(s);                                 \
        bj = (mask_lds[tn] != 0.f) ? bnew : bj;                              \
        Mref = Mnext;                                                        \
    }                                                                        \
    if (l < 32) (OUTP)[w * 32 + l] = bj; }

// 8 segments (sizes 58x6, 82, 81; boundaries 58,116,174,232,290,348,430).
// 8 groups x 32 chains = 256 blocks, 1/CU. At boundary k: FA_k (fwd-arriving),
// FB_k (bwd-arriving). FA_1 exact (grp0 phase1); FB_k = full bwd over segment
// k+1 (grp k phase1, k=1..7). FA_k (k=2..7) = L=24-step DIRECTION probes
// (scale cancels in the telescoped formula) appended as phase2 to grps 0..5.
// ws: [0..31] logZ | [32..63] numerator | 64 + slot*8192 + b*256 + j
//   slots: FA_k -> k-1 (0..6), FB_k -> 6+k (7..13)
__global__ __launch_bounds__(512, 1) void crf_seg_kernel(
    const float* __restrict__ emissions,    // [B,T,K]
    const int* __restrict__ mask,           // [B,T] (bool -> int32)
    const float* __restrict__ trans,        // [K,K]
    float* __restrict__ ws)
{
    const int tid = threadIdx.x;
    const int w = tid >> 6;
    const int l = tid & 63;
    const int ko8 = ((l >> 4) & 3) * 8;
    const int colg = w * 32 + (l & 15);
    const int nsel = (l >> 4) & 1;
    const int sj = w * 32 + nsel * 16 + (l & 15);
    const int grp = blockIdx.x >> 5;         // 0..7, block-uniform
    const int b = blockIdx.x & 31;

    __shared__ __align__(16) _Float16 pbuf[2][CK];
    __shared__ __align__(16) float wmaxl[2][8];
    __shared__ float mask_lds[CT];

    const float* emB = emissions + (size_t)b * CT * CK;
    const int* maskB = mask + b * CT;
    mask_lds[tid] = maskB[tid] ? 1.f : 0.f;

    // phase-1 ranges: grp0 fwd [1,58]; grp1..5 bwd [59+58(g-1), 116+58(g-1)];
    // grp6 bwd [349,430]; grp7 bwd [431,511]
    const int lo1 = (grp == 0) ? 1 : (grp <= 5) ? (1 + 58 * grp)
                   : (grp == 6) ? 349 : 431;
    const int hi1 = (grp == 0) ? 58 : (grp <= 5) ? (58 + 58 * grp)
                   : (grp == 6) ? 430 : 511;
    const int slot1 = (grp == 0) ? 0 : (6 + grp);
    float* const out1 = ws + 64 + (size_t)slot1 * CB * CK + (size_t)b * CK;

    if (grp == 0) {
        FWD_RUN(1, 58, emB[sj], out1)
    } else {
        BWD_RUN(lo1, hi1, out1)
    }

    if (grp <= 5) {
        // phase 2: direction probe FA_{grp+2} over last 24 steps before
        // boundary grp+2 (= hi of segment grp+2).
        const int phi = (grp <= 4) ? (116 + 58 * grp) : 430;
        const int plo = phi - 23;
        float* const out2 = ws + 64 + (size_t)(grp + 1) * CB * CK + (size_t)b * CK;
        __syncthreads();   // order phase-1 LDS reads before phase-2 writes
        FWD_RUN(plo, phi, 0.f, out2)
    }
}

__device__ inline float block_lse(float v, float* red, int tid) {
    const int wid = tid >> 6, lane = tid & 63;
    float mx = v;
    #pragma unroll
    for (int off = 32; off > 0; off >>= 1) mx = fmaxf(mx, __shfl_down(mx, off, 64));
    mx = __shfl(mx, 0, 64);
    if (lane == 0) red[wid] = mx;
    __syncthreads();
    const float g = fmaxf(fmaxf(red[0], red[1]), fmaxf(red[2], red[3]));
    float ex = __expf(v - g);
    #pragma unroll
    for (int off = 32; off > 0; off >>= 1) ex += __shfl_down(ex, off, 64);
    if (lane == 0) red[4 + wid] = ex;
    __syncthreads();
    const float r = g + __logf(red[4] + red[5] + red[6] + red[7]);
    __syncthreads();
    return r;
}

// Numerator + telescoped logZ:
// logZ = LSE(FA1+FB1) + sum_{k=2..7} [LSE(FA_k+FB_k) - LSE(FA_k)]
__global__ void crf_combine_kernel(const float* __restrict__ emissions,
                                   const int* __restrict__ tags,
                                   const int* __restrict__ mask,
                                   const float* __restrict__ trans,
                                   float* __restrict__ ws) {
    const int b = blockIdx.x;
    const int tid = threadIdx.x;                 // 256 threads
    const int wid = tid >> 6, lane = tid & 63;
    __shared__ float red[8];
    const float* emB = emissions + (size_t)b * CT * CK;
    const int* tagB = tags + b * CT;
    const int* maskB = mask + b * CT;

    float num = 0.f;
    for (int t = tid; t < CT; t += 256) {
        const float mf = maskB[t] ? 1.f : 0.f;
        num += emB[(size_t)t * CK + tagB[t]] * mf;
        if (t >= 1) num += trans[(size_t)tagB[t - 1] * CK + tagB[t]] * mf;
    }
    #pragma unroll
    for (int off = 32; off > 0; off >>= 1) num += __shfl_down(num, off, 64);
    if (lane == 0) red[wid] = num;
    __syncthreads();
    if (tid == 0) ws[CB + b] = red[0] + red[1] + red[2] + red[3];
    __syncthreads();

    const float* base = ws + 64;
    float r;
    {
        const float FA1 = base[0 * CB * CK + b * CK + tid];
        const float FB1 = base[7 * CB * CK + b * CK + tid];
        r = block_lse(FA1 + FB1, red, tid);
    }
    #pragma unroll
    for (int k = 2; k <= 7; ++k) {
        const float FAk = base[(size_t)(k - 1) * CB * CK + b * CK + tid];
        const float FBk = base[(size_t)(6 + k) * CB * CK + b * CK + tid];
        r += block_lse(FAk + FBk, red, tid);
        r -= block_lse(FAk, red, tid);
    }
    if (tid == 0) ws[b] = r;
}

__global__ void crf_finalize_kernel(const float* __restrict__ ws,
                                    float* __restrict__ out) {
    float v = 0.f;
    if ((int)threadIdx.x < CB) v = ws[threadIdx.x] - ws[CB + threadIdx.x];
    #pragma unroll
    for (int off = 32; off > 0; off >>= 1) v += __shfl_down(v, off, 64);
    if (threadIdx.x == 0) out[0] = v * (1.f / CB);
}

extern "C" void kernel_launch(void* const* d_in, const int* in_sizes, int n_in,
                              void* d_out, int out_size, void* d_ws, size_t ws_size,
                              hipStream_t stream) {
    const float* emissions = (const float*)d_in[0];
    const int* tags = (const int*)d_in[1];
    const int* mask = (const int*)d_in[2];
    const float* trans = (const float*)d_in[3];
    float* out = (float*)d_out;
    float* ws = (float*)d_ws;

    crf_seg_kernel<<<8 * CB, 512, 0, stream>>>(emissions, mask, trans, ws);
    crf_combine_kernel<<<CB, 256, 0, stream>>>(emissions, tags, mask, trans, ws);
    crf_finalize_kernel<<<1, 64, 0, stream>>>(ws, out);
}

// Round 21
// 71.239 us; speedup vs baseline: 5.2952x; 1.0708x over previous
//
#include <hip/hip_runtime.h>
#include <stdint.h>

#define CB 32
#define CT 512
#define CK 256
#define SHIFT 5.0f

typedef _Float16 f16x8 __attribute__((ext_vector_type(8)));
typedef float f32x4 __attribute__((ext_vector_type(4)));

__device__ inline uint32_t pk2(float a, float b) {
    return __builtin_bit_cast(uint32_t,
        __builtin_amdgcn_cvt_pkrtz(__expf(a), __expf(b)));
}

// Barrier draining LDS only; global prefetches stay in flight.
__device__ inline void lds_barrier() {
    asm volatile("s_waitcnt lgkmcnt(0)\n\ts_barrier" ::: "memory");
}

template <int CTRL>
__device__ inline float dpp_maxf(float x) {
    int yi = __builtin_amdgcn_update_dpp(
        __builtin_bit_cast(int, x), __builtin_bit_cast(int, x),
        CTRL, 0xF, 0xF, false);
    return fmaxf(x, __builtin_bit_cast(float, yi));
}

__device__ inline float wave_max(float x) {
    x = dpp_maxf<0x111>(x);
    x = dpp_maxf<0x112>(x);
    x = dpp_maxf<0x114>(x);
    x = dpp_maxf<0x118>(x);
    x = dpp_maxf<0x142>(x);
    x = dpp_maxf<0x143>(x);
    return __builtin_bit_cast(float,
        __builtin_amdgcn_readlane(__builtin_bit_cast(int, x), 63));
}

// FWD B-frag: B[k][col] = exp(trans[k][col]) (strided rows).
#define MKB_F(kt, n) f16x8 B_##kt##_##n; {                                   \
    const float* tp = trans + (size_t)((kt) * 32 + ko8) * CK + (colg + (n) * 16); \
    uint4 u_;                                                                \
    u_.x = pk2(tp[0],      tp[CK]);                                          \
    u_.y = pk2(tp[2 * CK], tp[3 * CK]);                                      \
    u_.z = pk2(tp[4 * CK], tp[5 * CK]);                                      \
    u_.w = pk2(tp[6 * CK], tp[7 * CK]);                                      \
    B_##kt##_##n = __builtin_bit_cast(f16x8, u_); }

// BWD B-frag: B[k][col] = exp(trans[col][k]) (contiguous k).
#define MKB_B(kt, n) f16x8 B_##kt##_##n; {                                   \
    const float* tp = trans + (size_t)(colg + (n) * 16) * CK + ((kt) * 32 + ko8); \
    uint4 u_;                                                                \
    u_.x = pk2(tp[0], tp[1]);                                                \
    u_.y = pk2(tp[2], tp[3]);                                                \
    u_.z = pk2(tp[4], tp[5]);                                                \
    u_.w = pk2(tp[6], tp[7]);                                                \
    B_##kt##_##n = __builtin_bit_cast(f16x8, u_); }

#define LOADB(MK) MK(0,0) MK(0,1) MK(1,0) MK(1,1) MK(2,0) MK(2,1) MK(3,0) MK(3,1) \
                  MK(4,0) MK(4,1) MK(5,0) MK(5,1) MK(6,0) MK(6,1) MK(7,0) MK(7,1)

#define MM(kt)                                                               \
    accA = __builtin_amdgcn_mfma_f32_16x16x32_f16(a##kt##_, B_##kt##_0, accA, 0, 0, 0); \
    accB = __builtin_amdgcn_mfma_f32_16x16x32_f16(a##kt##_, B_##kt##_1, accB, 0, 0, 0);

#define MFMA_STEP(pb)                                                        \
    f16x8 a0_ = *reinterpret_cast<const f16x8*>((pb) + 0   + ko8);           \
    f16x8 a1_ = *reinterpret_cast<const f16x8*>((pb) + 32  + ko8);           \
    f16x8 a2_ = *reinterpret_cast<const f16x8*>((pb) + 64  + ko8);           \
    f16x8 a3_ = *reinterpret_cast<const f16x8*>((pb) + 96  + ko8);           \
    f16x8 a4_ = *reinterpret_cast<const f16x8*>((pb) + 128 + ko8);           \
    f16x8 a5_ = *reinterpret_cast<const f16x8*>((pb) + 160 + ko8);           \
    f16x8 a6_ = *reinterpret_cast<const f16x8*>((pb) + 192 + ko8);           \
    f16x8 a7_ = *reinterpret_cast<const f16x8*>((pb) + 224 + ko8);           \
    f32x4 accA = {0.f, 0.f, 0.f, 0.f};                                       \
    f32x4 accB = {0.f, 0.f, 0.f, 0.f};                                       \
    MM(0) MM(1) MM(2) MM(3) MM(4) MM(5) MM(6) MM(7)

// Full fwd run over t in [T_LO, T_HI], alpha init AJ_INIT, result -> OUTP.
#define FWD_RUN(T_LO, T_HI, AJ_INIT, OUTP) {                                 \
    LOADB(MKB_F)                                                             \
    float aj = (AJ_INIT);                                                    \
    float emit_next = emB[(size_t)(T_LO) * CK + sj];                         \
    {   const float mw = wave_max(aj);                                       \
        if (l == 0) wmaxl[0][w] = mw; }                                      \
    __syncthreads();                                                         \
    float Mref;                                                              \
    {   const float4 wa = *reinterpret_cast<const float4*>(&wmaxl[0][0]);    \
        const float4 wb = *reinterpret_cast<const float4*>(&wmaxl[0][4]);    \
        Mref = fmaxf(fmaxf(fmaxf(wa.x, wa.y), fmaxf(wa.z, wa.w)),            \
                     fmaxf(fmaxf(wb.x, wb.y), fmaxf(wb.z, wb.w))) + SHIFT; } \
    __syncthreads();                                                         \
    for (int t = (T_LO); t <= (T_HI); ++t) {                                 \
        const float emit_t = emit_next;                                      \
        const int nxt = (t + 1 <= (T_HI)) ? (t + 1) : (T_HI);                \
        emit_next = emB[(size_t)nxt * CK + sj];                              \
        const int bsel = t & 1;                                              \
        const float mw = wave_max(aj);                                       \
        if (l == 0) wmaxl[bsel][w] = mw;                                     \
        const float pv = __expf(aj - Mref);                                  \
        if (l < 32) pbuf[bsel][w * 32 + l] = (_Float16)pv;                   \
        lds_barrier();                                                       \
        const float4 wa = *reinterpret_cast<const float4*>(&wmaxl[bsel][0]); \
        const float4 wb = *reinterpret_cast<const float4*>(&wmaxl[bsel][4]); \
        const float Mnext = fmaxf(fmaxf(fmaxf(wa.x, wa.y), fmaxf(wa.z, wa.w)), \
                                  fmaxf(fmaxf(wb.x, wb.y), fmaxf(wb.z, wb.w))) + SHIFT; \
        MFMA_STEP(pbuf[bsel])                                                \
        const float s = nsel ? accB[0] : accA[0];                            \
        const float anew = Mref + __logf(s) + emit_t;                        \
        aj = (mask_lds[t] != 0.f) ? anew : aj;                               \
        Mref = Mnext;                                                        \
    }                                                                        \
    if (l < 32) (OUTP)[w * 32 + l] = aj; }

// Full bwd run over tn in [TN_HI down to TN_LO], 0-init, result -> OUTP.
#define BWD_RUN(TN_LO, TN_HI, OUTP) {                                        \
    LOADB(MKB_B)                                                             \
    float bj = 0.f;                                                          \
    float emit_next = emB[(size_t)(TN_HI) * CK + sj];                        \
    __syncthreads();                                                         \
    {   const float mw = wave_max(bj + emit_next);                           \
        if (l == 0) wmaxl[0][w] = mw; }                                      \
    __syncthreads();                                                         \
    float Mref;                                                              \
    {   const float4 wa = *reinterpret_cast<const float4*>(&wmaxl[0][0]);    \
        const float4 wb = *reinterpret_cast<const float4*>(&wmaxl[0][4]);    \
        Mref = fmaxf(fmaxf(fmaxf(wa.x, wa.y), fmaxf(wa.z, wa.w)),            \
                     fmaxf(fmaxf(wb.x, wb.y), fmaxf(wb.z, wb.w))) + SHIFT; } \
    __syncthreads();                                                         \
    for (int tn = (TN_HI); tn >= (TN_LO); --tn) {                            \
        const float emit_t = emit_next;                                      \
        const int nxt = (tn - 1 > (TN_LO)) ? (tn - 1) : (TN_LO);             \
        emit_next = emB[(size_t)nxt * CK + sj];                              \
        const int bsel = tn & 1;                                             \
        const float v = bj + emit_t;                                         \
        const float mw = wave_max(v);                                        \
        if (l == 0) wmaxl[bsel][w] = mw;                                     \
        const float pv = __expf(v - Mref);                                   \
        if (l < 32) pbuf[bsel][w * 32 + l] = (_Float16)pv;                   \
        lds_barrier();                                                       \
        const float4 wa = *reinterpret_cast<const float4*>(&wmaxl[bsel][0]); \
        const float4 wb = *reinterpret_cast<const float4*>(&wmaxl[bsel][4]); \
        const float Mnext = fmaxf(fmaxf(fmaxf(wa.x, wa.y), fmaxf(wa.z, wa.w)), \
                                  fmaxf(fmaxf(wb.x, wb.y), fmaxf(wb.z, wb.w))) + SHIFT; \
        MFMA_STEP(pbuf[bsel])                                                \
        const float s = nsel ? accB[0] : accA[0];                            \
        const float bnew = Mref + __logf(s);                                 \
        bj = (mask_lds[tn] != 0.f) ? bnew : bj;                              \
        Mref = Mnext;                                                        \
    }                                                                        \
    if (l < 32) (OUTP)[w * 32 + l] = bj; }

// 8 segments, sizes {61 x6, 73, 72}; boundaries b_k = 61k (k=1..6), b7 = 439.
// 8 groups x 32 chains = 256 blocks, 1/CU. FA_1 exact (grp0 phase1);
// FB_k = full bwd over segment k+1 (grp k phase1, k=1..7). FA_k (k=2..7) =
// L=12-step DIRECTION probes (scale cancels in the telescope) as phase2 on
// grps 0..5. Max steps/group = 73.
// ws: [0..31] logZ | [32..63] numerator | 64 + slot*8192 + b*256 + j
//   slots: FA_k -> k-1 (0..6), FB_k -> 6+k (7..13)
__global__ __launch_bounds__(512, 1) void crf_seg_kernel(
    const float* __restrict__ emissions,    // [B,T,K]
    const int* __restrict__ mask,           // [B,T] (bool -> int32)
    const float* __restrict__ trans,        // [K,K]
    float* __restrict__ ws)
{
    const int tid = threadIdx.x;
    const int w = tid >> 6;
    const int l = tid & 63;
    const int ko8 = ((l >> 4) & 3) * 8;
    const int colg = w * 32 + (l & 15);
    const int nsel = (l >> 4) & 1;
    const int sj = w * 32 + nsel * 16 + (l & 15);
    const int grp = blockIdx.x >> 5;         // 0..7, block-uniform
    const int b = blockIdx.x & 31;

    __shared__ __align__(16) _Float16 pbuf[2][CK];
    __shared__ __align__(16) float wmaxl[2][8];
    __shared__ float mask_lds[CT];

    const float* emB = emissions + (size_t)b * CT * CK;
    const int* maskB = mask + b * CT;
    mask_lds[tid] = maskB[tid] ? 1.f : 0.f;

    // phase-1 ranges: grp0 fwd [1,61]; grp1..5 bwd [1+61g, 61+61g];
    // grp6 bwd [367,439]; grp7 bwd [440,511]
    const int lo1 = (grp == 0) ? 1 : (grp <= 5) ? (1 + 61 * grp)
                   : (grp == 6) ? 367 : 440;
    const int hi1 = (grp == 0) ? 61 : (grp <= 5) ? (61 + 61 * grp)
                   : (grp == 6) ? 439 : 511;
    const int slot1 = (grp == 0) ? 0 : (6 + grp);
    float* const out1 = ws + 64 + (size_t)slot1 * CB * CK + (size_t)b * CK;

    if (grp == 0) {
        FWD_RUN(1, 61, emB[sj], out1)
    } else {
        BWD_RUN(lo1, hi1, out1)
    }

    if (grp <= 5) {
        // phase 2: direction probe FA_{grp+2} over last 12 steps before
        // boundary grp+2 (b_k = 61k for k<=6, b7 = 439).
        const int phi = (grp <= 4) ? (122 + 61 * grp) : 439;
        const int plo = phi - 11;
        float* const out2 = ws + 64 + (size_t)(grp + 1) * CB * CK + (size_t)b * CK;
        __syncthreads();   // order phase-1 LDS reads before phase-2 writes
        FWD_RUN(plo, phi, 0.f, out2)
    }
}

__device__ inline float block_lse(float v, float* red, int tid) {
    const int wid = tid >> 6, lane = tid & 63;
    float mx = v;
    #pragma unroll
    for (int off = 32; off > 0; off >>= 1) mx = fmaxf(mx, __shfl_down(mx, off, 64));
    mx = __shfl(mx, 0, 64);
    if (lane == 0) red[wid] = mx;
    __syncthreads();
    const float g = fmaxf(fmaxf(red[0], red[1]), fmaxf(red[2], red[3]));
    float ex = __expf(v - g);
    #pragma unroll
    for (int off = 32; off > 0; off >>= 1) ex += __shfl_down(ex, off, 64);
    if (lane == 0) red[4 + wid] = ex;
    __syncthreads();
    const float r = g + __logf(red[4] + red[5] + red[6] + red[7]);
    __syncthreads();
    return r;
}

// Numerator + telescoped logZ:
// logZ = LSE(FA1+FB1) + sum_{k=2..7} [LSE(FA_k+FB_k) - LSE(FA_k)]
__global__ void crf_combine_kernel(const float* __restrict__ emissions,
                                   const int* __restrict__ tags,
                                   const int* __restrict__ mask,
                                   const float* __restrict__ trans,
                                   float* __restrict__ ws) {
    const int b = blockIdx.x;
    const int tid = threadIdx.x;                 // 256 threads
    const int wid = tid >> 6, lane = tid & 63;
    __shared__ float red[8];
    const float* emB = emissions + (size_t)b * CT * CK;
    const int* tagB = tags + b * CT;
    const int* maskB = mask + b * CT;

    float num = 0.f;
    for (int t = tid; t < CT; t += 256) {
        const float mf = maskB[t] ? 1.f : 0.f;
        num += emB[(size_t)t * CK + tagB[t]] * mf;
        if (t >= 1) num += trans[(size_t)tagB[t - 1] * CK + tagB[t]] * mf;
    }
    #pragma unroll
    for (int off = 32; off > 0; off >>= 1) num += __shfl_down(num, off, 64);
    if (lane == 0) red[wid] = num;
    __syncthreads();
    if (tid == 0) ws[CB + b] = red[0] + red[1] + red[2] + red[3];
    __syncthreads();

    const float* base = ws + 64;
    float r;
    {
        const float FA1 = base[0 * CB * CK + b * CK + tid];
        const float FB1 = base[7 * CB * CK + b * CK + tid];
        r = block_lse(FA1 + FB1, red, tid);
    }
    #pragma unroll
    for (int k = 2; k <= 7; ++k) {
        const float FAk = base[(size_t)(k - 1) * CB * CK + b * CK + tid];
        const float FBk = base[(size_t)(6 + k) * CB * CK + b * CK + tid];
        r += block_lse(FAk + FBk, red, tid);
        r -= block_lse(FAk, red, tid);
    }
    if (tid == 0) ws[b] = r;
}

__global__ void crf_finalize_kernel(const float* __restrict__ ws,
                                    float* __restrict__ out) {
    float v = 0.f;
    if ((int)threadIdx.x < CB) v = ws[threadIdx.x] - ws[CB + threadIdx.x];
    #pragma unroll
    for (int off = 32; off > 0; off >>= 1) v += __shfl_down(v, off, 64);
    if (threadIdx.x == 0) out[0] = v * (1.f / CB);
}

extern "C" void kernel_launch(void* const* d_in, const int* in_sizes, int n_in,
                              void* d_out, int out_size, void* d_ws, size_t ws_size,
                              hipStream_t stream) {
    const float* emissions = (const float*)d_in[0];
    const int* tags = (const int*)d_in[1];
    const int* mask = (const int*)d_in[2];
    const float* trans = (const float*)d_in[3];
    float* out = (float*)d_out;
    float* ws = (float*)d_ws;

    crf_seg_kernel<<<8 * CB, 512, 0, stream>>>(emissions, mask, trans, ws);
    crf_combine_kernel<<<CB, 256, 0, stream>>>(emissions, tags, mask, trans, ws);
    crf_finalize_kernel<<<1, 64, 0, stream>>>(ws, out);
}

// Round 22
// 69.278 us; speedup vs baseline: 5.4451x; 1.0283x over previous
//
#include <hip/hip_runtime.h>
#include <stdint.h>

#define CB 32
#define CT 512
#define CK 256
#define SHIFT 5.0f

typedef _Float16 f16x8 __attribute__((ext_vector_type(8)));
typedef float f32x4 __attribute__((ext_vector_type(4)));

__device__ inline uint32_t pk2(float a, float b) {
    return __builtin_bit_cast(uint32_t,
        __builtin_amdgcn_cvt_pkrtz(__expf(a), __expf(b)));
}

// Barrier draining LDS only; global prefetches stay in flight.
__device__ inline void lds_barrier() {
    asm volatile("s_waitcnt lgkmcnt(0)\n\ts_barrier" ::: "memory");
}

template <int CTRL>
__device__ inline float dpp_maxf(float x) {
    int yi = __builtin_amdgcn_update_dpp(
        __builtin_bit_cast(int, x), __builtin_bit_cast(int, x),
        CTRL, 0xF, 0xF, false);
    return fmaxf(x, __builtin_bit_cast(float, yi));
}

__device__ inline float wave_max(float x) {
    x = dpp_maxf<0x111>(x);
    x = dpp_maxf<0x112>(x);
    x = dpp_maxf<0x114>(x);
    x = dpp_maxf<0x118>(x);
    x = dpp_maxf<0x142>(x);
    x = dpp_maxf<0x143>(x);
    return __builtin_bit_cast(float,
        __builtin_amdgcn_readlane(__builtin_bit_cast(int, x), 63));
}

// FWD B-frag: B[k][col] = exp(trans[k][col]) (strided rows).
#define MKB_F(kt, n) f16x8 B_##kt##_##n; {                                   \
    const float* tp = trans + (size_t)((kt) * 32 + ko8) * CK + (colg + (n) * 16); \
    uint4 u_;                                                                \
    u_.x = pk2(tp[0],      tp[CK]);                                          \
    u_.y = pk2(tp[2 * CK], tp[3 * CK]);                                      \
    u_.z = pk2(tp[4 * CK], tp[5 * CK]);                                      \
    u_.w = pk2(tp[6 * CK], tp[7 * CK]);                                      \
    B_##kt##_##n = __builtin_bit_cast(f16x8, u_); }

// BWD B-frag: B[k][col] = exp(trans[col][k]) (contiguous k).
#define MKB_B(kt, n) f16x8 B_##kt##_##n; {                                   \
    const float* tp = trans + (size_t)(colg + (n) * 16) * CK + ((kt) * 32 + ko8); \
    uint4 u_;                                                                \
    u_.x = pk2(tp[0], tp[1]);                                                \
    u_.y = pk2(tp[2], tp[3]);                                                \
    u_.z = pk2(tp[4], tp[5]);                                                \
    u_.w = pk2(tp[6], tp[7]);                                                \
    B_##kt##_##n = __builtin_bit_cast(f16x8, u_); }

#define LOADB(MK) MK(0,0) MK(0,1) MK(1,0) MK(1,1) MK(2,0) MK(2,1) MK(3,0) MK(3,1) \
                  MK(4,0) MK(4,1) MK(5,0) MK(5,1) MK(6,0) MK(6,1) MK(7,0) MK(7,1)

#define MM(kt)                                                               \
    accA = __builtin_amdgcn_mfma_f32_16x16x32_f16(a##kt##_, B_##kt##_0, accA, 0, 0, 0); \
    accB = __builtin_amdgcn_mfma_f32_16x16x32_f16(a##kt##_, B_##kt##_1, accB, 0, 0, 0);

#define MFMA_STEP(pb)                                                        \
    f16x8 a0_ = *reinterpret_cast<const f16x8*>((pb) + 0   + ko8);           \
    f16x8 a1_ = *reinterpret_cast<const f16x8*>((pb) + 32  + ko8);           \
    f16x8 a2_ = *reinterpret_cast<const f16x8*>((pb) + 64  + ko8);           \
    f16x8 a3_ = *reinterpret_cast<const f16x8*>((pb) + 96  + ko8);           \
    f16x8 a4_ = *reinterpret_cast<const f16x8*>((pb) + 128 + ko8);           \
    f16x8 a5_ = *reinterpret_cast<const f16x8*>((pb) + 160 + ko8);           \
    f16x8 a6_ = *reinterpret_cast<const f16x8*>((pb) + 192 + ko8);           \
    f16x8 a7_ = *reinterpret_cast<const f16x8*>((pb) + 224 + ko8);           \
    f32x4 accA = {0.f, 0.f, 0.f, 0.f};                                       \
    f32x4 accB = {0.f, 0.f, 0.f, 0.f};                                       \
    MM(0) MM(1) MM(2) MM(3) MM(4) MM(5) MM(6) MM(7)

// Full fwd run over t in [T_LO, T_HI], alpha init AJ_INIT, result -> OUTP.
#define FWD_RUN(T_LO, T_HI, AJ_INIT, OUTP) {                                 \
    LOADB(MKB_F)                                                             \
    float aj = (AJ_INIT);                                                    \
    float emit_next = emB[(size_t)(T_LO) * CK + sj];                         \
    {   const float mw = wave_max(aj);                                       \
        if (l == 0) wmaxl[0][w] = mw; }                                      \
    __syncthreads();                                                         \
    float Mref;                                                              \
    {   const float4 wa = *reinterpret_cast<const float4*>(&wmaxl[0][0]);    \
        const float4 wb = *reinterpret_cast<const float4*>(&wmaxl[0][4]);    \
        Mref = fmaxf(fmaxf(fmaxf(wa.x, wa.y), fmaxf(wa.z, wa.w)),            \
                     fmaxf(fmaxf(wb.x, wb.y), fmaxf(wb.z, wb.w))) + SHIFT; } \
    __syncthreads();                                                         \
    for (int t = (T_LO); t <= (T_HI); ++t) {                                 \
        const float emit_t = emit_next;                                      \
        const int nxt = (t + 1 <= (T_HI)) ? (t + 1) : (T_HI);                \
        emit_next = emB[(size_t)nxt * CK + sj];                              \
        const int bsel = t & 1;                                              \
        const float mw = wave_max(aj);                                       \
        if (l == 0) wmaxl[bsel][w] = mw;                                     \
        const float pv = __expf(aj - Mref);                                  \
        if (l < 32) pbuf[bsel][w * 32 + l] = (_Float16)pv;                   \
        lds_barrier();                                                       \
        const float4 wa = *reinterpret_cast<const float4*>(&wmaxl[bsel][0]); \
        const float4 wb = *reinterpret_cast<const float4*>(&wmaxl[bsel][4]); \
        const float Mnext = fmaxf(fmaxf(fmaxf(wa.x, wa.y), fmaxf(wa.z, wa.w)), \
                                  fmaxf(fmaxf(wb.x, wb.y), fmaxf(wb.z, wb.w))) + SHIFT; \
        MFMA_STEP(pbuf[bsel])                                                \
        const float s = nsel ? accB[0] : accA[0];                            \
        const float anew = Mref + __logf(s) + emit_t;                        \
        aj = (mask_lds[t] != 0.f) ? anew : aj;                               \
        Mref = Mnext;                                                        \
    }                                                                        \
    if (l < 32) (OUTP)[w * 32 + l] = aj; }

// Full bwd run over tn in [TN_HI down to TN_LO], 0-init, result -> OUTP.
#define BWD_RUN(TN_LO, TN_HI, OUTP) {                                        \
    LOADB(MKB_B)                                                             \
    float bj = 0.f;                                                          \
    float emit_next = emB[(size_t)(TN_HI) * CK + sj];                        \
    __syncthreads();                                                         \
    {   const float mw = wave_max(bj + emit_next);                           \
        if (l == 0) wmaxl[0][w] = mw; }                                      \
    __syncthreads();                                                         \
    float Mref;                                                              \
    {   const float4 wa = *reinterpret_cast<const float4*>(&wmaxl[0][0]);    \
        const float4 wb = *reinterpret_cast<const float4*>(&wmaxl[0][4]);    \
        Mref = fmaxf(fmaxf(fmaxf(wa.x, wa.y), fmaxf(wa.z, wa.w)),            \
                     fmaxf(fmaxf(wb.x, wb.y), fmaxf(wb.z, wb.w))) + SHIFT; } \
    __syncthreads();                                                         \
    for (int tn = (TN_HI); tn >= (TN_LO); --tn) {                            \
        const float emit_t = emit_next;                                      \
        const int nxt = (tn - 1 > (TN_LO)) ? (tn - 1) : (TN_LO);             \
        emit_next = emB[(size_t)nxt * CK + sj];                              \
        const int bsel = tn & 1;                                             \
        const float v = bj + emit_t;                                         \
        const float mw = wave_max(v);                                        \
        if (l == 0) wmaxl[bsel][w] = mw;                                     \
        const float pv = __expf(v - Mref);                                   \
        if (l < 32) pbuf[bsel][w * 32 + l] = (_Float16)pv;                   \
        lds_barrier();                                                       \
        const float4 wa = *reinterpret_cast<const float4*>(&wmaxl[bsel][0]); \
        const float4 wb = *reinterpret_cast<const float4*>(&wmaxl[bsel][4]); \
        const float Mnext = fmaxf(fmaxf(fmaxf(wa.x, wa.y), fmaxf(wa.z, wa.w)), \
                                  fmaxf(fmaxf(wb.x, wb.y), fmaxf(wb.z, wb.w))) + SHIFT; \
        MFMA_STEP(pbuf[bsel])                                                \
        const float s = nsel ? accB[0] : accA[0];                            \
        const float bnew = Mref + __logf(s);                                 \
        bj = (mask_lds[tn] != 0.f) ? bnew : bj;                              \
        Mref = Mnext;                                                        \
    }                                                                        \
    if (l < 32) (OUTP)[w * 32 + l] = bj; }

// 8 segments, sizes {63 x6, 67, 66}; boundaries b_k = 63k (k=1..6), b7 = 445.
// 8 groups x 32 chains = 256 blocks, 1/CU. FA_1 exact (grp0 phase1);
// FB_k = full bwd over segment k+1 (grp k phase1, k=1..7). FA_k (k=2..7) =
// L=6-step DIRECTION probes (scale cancels in the telescope) as phase2 on
// grps 0..5. Max steps/group = 69.
// ws: [0..31] logZ | [32..63] numerator | 64 + slot*8192 + b*256 + j
//   slots: FA_k -> k-1 (0..6), FB_k -> 6+k (7..13)
__global__ __launch_bounds__(512, 1) void crf_seg_kernel(
    const float* __restrict__ emissions,    // [B,T,K]
    const int* __restrict__ mask,           // [B,T] (bool -> int32)
    const float* __restrict__ trans,        // [K,K]
    float* __restrict__ ws)
{
    const int tid = threadIdx.x;
    const int w = tid >> 6;
    const int l = tid & 63;
    const int ko8 = ((l >> 4) & 3) * 8;
    const int colg = w * 32 + (l & 15);
    const int nsel = (l >> 4) & 1;
    const int sj = w * 32 + nsel * 16 + (l & 15);
    const int grp = blockIdx.x >> 5;         // 0..7, block-uniform
    const int b = blockIdx.x & 31;

    __shared__ __align__(16) _Float16 pbuf[2][CK];
    __shared__ __align__(16) float wmaxl[2][8];
    __shared__ float mask_lds[CT];

    const float* emB = emissions + (size_t)b * CT * CK;
    const int* maskB = mask + b * CT;
    mask_lds[tid] = maskB[tid] ? 1.f : 0.f;

    // phase-1 ranges: grp0 fwd [1,63]; grp1..5 bwd [1+63g, 63+63g];
    // grp6 bwd [379,445]; grp7 bwd [446,511]
    const int lo1 = (grp == 0) ? 1 : (grp <= 5) ? (1 + 63 * grp)
                   : (grp == 6) ? 379 : 446;
    const int hi1 = (grp == 0) ? 63 : (grp <= 5) ? (63 + 63 * grp)
                   : (grp == 6) ? 445 : 511;
    const int slot1 = (grp == 0) ? 0 : (6 + grp);
    float* const out1 = ws + 64 + (size_t)slot1 * CB * CK + (size_t)b * CK;

    if (grp == 0) {
        FWD_RUN(1, 63, emB[sj], out1)
    } else {
        BWD_RUN(lo1, hi1, out1)
    }

    if (grp <= 5) {
        // phase 2: direction probe FA_{grp+2} over last 6 steps before
        // boundary grp+2 (b_k = 63k for k<=6, b7 = 445).
        const int phi = (grp <= 4) ? (126 + 63 * grp) : 445;
        const int plo = phi - 5;
        float* const out2 = ws + 64 + (size_t)(grp + 1) * CB * CK + (size_t)b * CK;
        __syncthreads();   // order phase-1 LDS reads before phase-2 writes
        FWD_RUN(plo, phi, 0.f, out2)
    }
}

__device__ inline float block_lse(float v, float* red, int tid) {
    const int wid = tid >> 6, lane = tid & 63;
    float mx = v;
    #pragma unroll
    for (int off = 32; off > 0; off >>= 1) mx = fmaxf(mx, __shfl_down(mx, off, 64));
    mx = __shfl(mx, 0, 64);
    if (lane == 0) red[wid] = mx;
    __syncthreads();
    const float g = fmaxf(fmaxf(red[0], red[1]), fmaxf(red[2], red[3]));
    float ex = __expf(v - g);
    #pragma unroll
    for (int off = 32; off > 0; off >>= 1) ex += __shfl_down(ex, off, 64);
    if (lane == 0) red[4 + wid] = ex;
    __syncthreads();
    const float r = g + __logf(red[4] + red[5] + red[6] + red[7]);
    __syncthreads();
    return r;
}

// Numerator + telescoped logZ:
// logZ = LSE(FA1+FB1) + sum_{k=2..7} [LSE(FA_k+FB_k) - LSE(FA_k)]
__global__ void crf_combine_kernel(const float* __restrict__ emissions,
                                   const int* __restrict__ tags,
                                   const int* __restrict__ mask,
                                   const float* __restrict__ trans,
                                   float* __restrict__ ws) {
    const int b = blockIdx.x;
    const int tid = threadIdx.x;                 // 256 threads
    const int wid = tid >> 6, lane = tid & 63;
    __shared__ float red[8];
    const float* emB = emissions + (size_t)b * CT * CK;
    const int* tagB = tags + b * CT;
    const int* maskB = mask + b * CT;

    float num = 0.f;
    for (int t = tid; t < CT; t += 256) {
        const float mf = maskB[t] ? 1.f : 0.f;
        num += emB[(size_t)t * CK + tagB[t]] * mf;
        if (t >= 1) num += trans[(size_t)tagB[t - 1] * CK + tagB[t]] * mf;
    }
    #pragma unroll
    for (int off = 32; off > 0; off >>= 1) num += __shfl_down(num, off, 64);
    if (lane == 0) red[wid] = num;
    __syncthreads();
    if (tid == 0) ws[CB + b] = red[0] + red[1] + red[2] + red[3];
    __syncthreads();

    const float* base = ws + 64;
    float r;
    {
        const float FA1 = base[0 * CB * CK + b * CK + tid];
        const float FB1 = base[7 * CB * CK + b * CK + tid];
        r = block_lse(FA1 + FB1, red, tid);
    }
    #pragma unroll
    for (int k = 2; k <= 7; ++k) {
        const float FAk = base[(size_t)(k - 1) * CB * CK + b * CK + tid];
        const float FBk = base[(size_t)(6 + k) * CB * CK + b * CK + tid];
        r += block_lse(FAk + FBk, red, tid);
        r -= block_lse(FAk, red, tid);
    }
    if (tid == 0) ws[b] = r;
}

__global__ void crf_finalize_kernel(const float* __restrict__ ws,
                                    float* __restrict__ out) {
    float v = 0.f;
    if ((int)threadIdx.x < CB) v = ws[threadIdx.x] - ws[CB + threadIdx.x];
    #pragma unroll
    for (int off = 32; off > 0; off >>= 1) v += __shfl_down(v, off, 64);
    if (threadIdx.x == 0) out[0] = v * (1.f / CB);
}

extern "C" void kernel_launch(void* const* d_in, const int* in_sizes, int n_in,
                              void* d_out, int out_size, void* d_ws, size_t ws_size,
                              hipStream_t stream) {
    const float* emissions = (const float*)d_in[0];
    const int* tags = (const int*)d_in[1];
    const int* mask = (const int*)d_in[2];
    const float* trans = (const float*)d_in[3];
    float* out = (float*)d_out;
    float* ws = (float*)d_ws;

    crf_seg_kernel<<<8 * CB, 512, 0, stream>>>(emissions, mask, trans, ws);
    crf_combine_kernel<<<CB, 256, 0, stream>>>(emissions, tags, mask, trans, ws);
    crf_finalize_kernel<<<1, 64, 0, stream>>>(ws, out);
}

// Round 23
// 68.262 us; speedup vs baseline: 5.5261x; 1.0149x over previous
//
#include <hip/hip_runtime.h>
#include <stdint.h>

#define CB 32
#define CT 512
#define CK 256
#define SHIFT 5.0f
#define NUMOFF (64 + 14 * CB * CK)   // numerator partials: [8][CB]

typedef _Float16 f16x8 __attribute__((ext_vector_type(8)));
typedef float f32x4 __attribute__((ext_vector_type(4)));

__device__ inline uint32_t pk2(float a, float b) {
    return __builtin_bit_cast(uint32_t,
        __builtin_amdgcn_cvt_pkrtz(__expf(a), __expf(b)));
}

// Barrier draining LDS only; global prefetches stay in flight.
__device__ inline void lds_barrier() {
    asm volatile("s_waitcnt lgkmcnt(0)\n\ts_barrier" ::: "memory");
}

template <int CTRL>
__device__ inline float dpp_maxf(float x) {
    int yi = __builtin_amdgcn_update_dpp(
        __builtin_bit_cast(int, x), __builtin_bit_cast(int, x),
        CTRL, 0xF, 0xF, false);
    return fmaxf(x, __builtin_bit_cast(float, yi));
}

__device__ inline float wave_max(float x) {
    x = dpp_maxf<0x111>(x);
    x = dpp_maxf<0x112>(x);
    x = dpp_maxf<0x114>(x);
    x = dpp_maxf<0x118>(x);
    x = dpp_maxf<0x142>(x);
    x = dpp_maxf<0x143>(x);
    return __builtin_bit_cast(float,
        __builtin_amdgcn_readlane(__builtin_bit_cast(int, x), 63));
}

// FWD B-frag: B[k][col] = exp(trans[k][col]) (strided rows).
#define MKB_F(kt, n) f16x8 B_##kt##_##n; {                                   \
    const float* tp = trans + (size_t)((kt) * 32 + ko8) * CK + (colg + (n) * 16); \
    uint4 u_;                                                                \
    u_.x = pk2(tp[0],      tp[CK]);                                          \
    u_.y = pk2(tp[2 * CK], tp[3 * CK]);                                      \
    u_.z = pk2(tp[4 * CK], tp[5 * CK]);                                      \
    u_.w = pk2(tp[6 * CK], tp[7 * CK]);                                      \
    B_##kt##_##n = __builtin_bit_cast(f16x8, u_); }

// BWD B-frag: B[k][col] = exp(trans[col][k]) (contiguous k).
#define MKB_B(kt, n) f16x8 B_##kt##_##n; {                                   \
    const float* tp = trans + (size_t)(colg + (n) * 16) * CK + ((kt) * 32 + ko8); \
    uint4 u_;                                                                \
    u_.x = pk2(tp[0], tp[1]);                                                \
    u_.y = pk2(tp[2], tp[3]);                                                \
    u_.z = pk2(tp[4], tp[5]);                                                \
    u_.w = pk2(tp[6], tp[7]);                                                \
    B_##kt##_##n = __builtin_bit_cast(f16x8, u_); }

#define LOADB(MK) MK(0,0) MK(0,1) MK(1,0) MK(1,1) MK(2,0) MK(2,1) MK(3,0) MK(3,1) \
                  MK(4,0) MK(4,1) MK(5,0) MK(5,1) MK(6,0) MK(6,1) MK(7,0) MK(7,1)

#define MM(kt)                                                               \
    accA = __builtin_amdgcn_mfma_f32_16x16x32_f16(a##kt##_, B_##kt##_0, accA, 0, 0, 0); \
    accB = __builtin_amdgcn_mfma_f32_16x16x32_f16(a##kt##_, B_##kt##_1, accB, 0, 0, 0);

#define MFMA_STEP(pb)                                                        \
    f16x8 a0_ = *reinterpret_cast<const f16x8*>((pb) + 0   + ko8);           \
    f16x8 a1_ = *reinterpret_cast<const f16x8*>((pb) + 32  + ko8);           \
    f16x8 a2_ = *reinterpret_cast<const f16x8*>((pb) + 64  + ko8);           \
    f16x8 a3_ = *reinterpret_cast<const f16x8*>((pb) + 96  + ko8);           \
    f16x8 a4_ = *reinterpret_cast<const f16x8*>((pb) + 128 + ko8);           \
    f16x8 a5_ = *reinterpret_cast<const f16x8*>((pb) + 160 + ko8);           \
    f16x8 a6_ = *reinterpret_cast<const f16x8*>((pb) + 192 + ko8);           \
    f16x8 a7_ = *reinterpret_cast<const f16x8*>((pb) + 224 + ko8);           \
    f32x4 accA = {0.f, 0.f, 0.f, 0.f};                                       \
    f32x4 accB = {0.f, 0.f, 0.f, 0.f};                                       \
    MM(0) MM(1) MM(2) MM(3) MM(4) MM(5) MM(6) MM(7)

// Full fwd run over t in [T_LO, T_HI], alpha init AJ_INIT, result -> OUTP.
#define FWD_RUN(T_LO, T_HI, AJ_INIT, OUTP) {                                 \
    LOADB(MKB_F)                                                             \
    float aj = (AJ_INIT);                                                    \
    float emit_next = emB[(size_t)(T_LO) * CK + sj];                         \
    {   const float mw = wave_max(aj);                                       \
        if (l == 0) wmaxl[0][w] = mw; }                                      \
    __syncthreads();                                                         \
    float Mref;                                                              \
    {   const float4 wa = *reinterpret_cast<const float4*>(&wmaxl[0][0]);    \
        const float4 wb = *reinterpret_cast<const float4*>(&wmaxl[0][4]);    \
        Mref = fmaxf(fmaxf(fmaxf(wa.x, wa.y), fmaxf(wa.z, wa.w)),            \
                     fmaxf(fmaxf(wb.x, wb.y), fmaxf(wb.z, wb.w))) + SHIFT; } \
    __syncthreads();                                                         \
    for (int t = (T_LO); t <= (T_HI); ++t) {                                 \
        const float emit_t = emit_next;                                      \
        const int nxt = (t + 1 <= (T_HI)) ? (t + 1) : (T_HI);                \
        emit_next = emB[(size_t)nxt * CK + sj];                              \
        const int bsel = t & 1;                                              \
        const float mw = wave_max(aj);                                       \
        if (l == 0) wmaxl[bsel][w] = mw;                                     \
        const float pv = __expf(aj - Mref);                                  \
        if (l < 32) pbuf[bsel][w * 32 + l] = (_Float16)pv;                   \
        lds_barrier();                                                       \
        const float4 wa = *reinterpret_cast<const float4*>(&wmaxl[bsel][0]); \
        const float4 wb = *reinterpret_cast<const float4*>(&wmaxl[bsel][4]); \
        const float Mnext = fmaxf(fmaxf(fmaxf(wa.x, wa.y), fmaxf(wa.z, wa.w)), \
                                  fmaxf(fmaxf(wb.x, wb.y), fmaxf(wb.z, wb.w))) + SHIFT; \
        MFMA_STEP(pbuf[bsel])                                                \
        const float s = nsel ? accB[0] : accA[0];                            \
        const float anew = Mref + __logf(s) + emit_t;                        \
        aj = (mask_lds[t] != 0.f) ? anew : aj;                               \
        Mref = Mnext;                                                        \
    }                                                                        \
    if (l < 32) (OUTP)[w * 32 + l] = aj; }

// Full bwd run over tn in [TN_HI down to TN_LO], 0-init, result -> OUTP.
#define BWD_RUN(TN_LO, TN_HI, OUTP) {                                        \
    LOADB(MKB_B)                                                             \
    float bj = 0.f;                                                          \
    float emit_next = emB[(size_t)(TN_HI) * CK + sj];                        \
    __syncthreads();                                                         \
    {   const float mw = wave_max(bj + emit_next);                           \
        if (l == 0) wmaxl[0][w] = mw; }                                      \
    __syncthreads();                                                         \
    float Mref;                                                              \
    {   const float4 wa = *reinterpret_cast<const float4*>(&wmaxl[0][0]);    \
        const float4 wb = *reinterpret_cast<const float4*>(&wmaxl[0][4]);    \
        Mref = fmaxf(fmaxf(fmaxf(wa.x, wa.y), fmaxf(wa.z, wa.w)),            \
                     fmaxf(fmaxf(wb.x, wb.y), fmaxf(wb.z, wb.w))) + SHIFT; } \
    __syncthreads();                                                         \
    for (int tn = (TN_HI); tn >= (TN_LO); --tn) {                            \
        const float emit_t = emit_next;                                      \
        const int nxt = (tn - 1 > (TN_LO)) ? (tn - 1) : (TN_LO);             \
        emit_next = emB[(size_t)nxt * CK + sj];                              \
        const int bsel = tn & 1;                                             \
        const float v = bj + emit_t;                                         \
        const float mw = wave_max(v);                                        \
        if (l == 0) wmaxl[bsel][w] = mw;                                     \
        const float pv = __expf(v - Mref);                                   \
        if (l < 32) pbuf[bsel][w * 32 + l] = (_Float16)pv;                   \
        lds_barrier();                                                       \
        const float4 wa = *reinterpret_cast<const float4*>(&wmaxl[bsel][0]); \
        const float4 wb = *reinterpret_cast<const float4*>(&wmaxl[bsel][4]); \
        const float Mnext = fmaxf(fmaxf(fmaxf(wa.x, wa.y), fmaxf(wa.z, wa.w)), \
                                  fmaxf(fmaxf(wb.x, wb.y), fmaxf(wb.z, wb.w))) + SHIFT; \
        MFMA_STEP(pbuf[bsel])                                                \
        const float s = nsel ? accB[0] : accA[0];                            \
        const float bnew = Mref + __logf(s);                                 \
        bj = (mask_lds[tn] != 0.f) ? bnew : bj;                              \
        Mref = Mnext;                                                        \
    }                                                                        \
    if (l < 32) (OUTP)[w * 32 + l] = bj; }

// 8 segments {64 x7, 63}; boundaries b_k = 64k (k=1..7).
// 8 groups x 32 chains = 256 blocks, 1/CU. FA_1 exact (grp0 phase1);
// FB_k = full bwd over segment k+1 (grp k phase1, k=1..7). FA_k (k=2..7) =
// L=3-step DIRECTION probes (scale cancels in the telescope) as phase2 on
// grps 0..5. Max steps/group = 67. Numerator partials: wave 0 of each block
// covers t in [64*grp, 64*grp+63] -> ws[NUMOFF + grp*CB + b].
// ws: [0..31] logZ | [32..63] numerator | 64 + slot*8192 + b*256 + j
//   slots: FA_k -> k-1 (0..6), FB_k -> 6+k (7..13) | NUMOFF: [8][CB] partials
__global__ __launch_bounds__(512, 1) void crf_seg_kernel(
    const float* __restrict__ emissions,    // [B,T,K]
    const int* __restrict__ tags,           // [B,T]
    const int* __restrict__ mask,           // [B,T] (bool -> int32)
    const float* __restrict__ trans,        // [K,K]
    float* __restrict__ ws)
{
    const int tid = threadIdx.x;
    const int w = tid >> 6;
    const int l = tid & 63;
    const int ko8 = ((l >> 4) & 3) * 8;
    const int colg = w * 32 + (l & 15);
    const int nsel = (l >> 4) & 1;
    const int sj = w * 32 + nsel * 16 + (l & 15);
    const int grp = blockIdx.x >> 5;         // 0..7, block-uniform
    const int b = blockIdx.x & 31;

    __shared__ __align__(16) _Float16 pbuf[2][CK];
    __shared__ __align__(16) float wmaxl[2][8];
    __shared__ float mask_lds[CT];

    const float* emB = emissions + (size_t)b * CT * CK;
    const int* tagB = tags + b * CT;
    const int* maskB = mask + b * CT;
    mask_lds[tid] = maskB[tid] ? 1.f : 0.f;

    // numerator partial: wave 0, t = 64*grp + l
    if (tid < 64) {
        const int t = 64 * grp + l;
        const float mf = maskB[t] ? 1.f : 0.f;
        float num = emB[(size_t)t * CK + tagB[t]] * mf;
        if (t >= 1) num += trans[(size_t)tagB[t - 1] * CK + tagB[t]] * mf;
        #pragma unroll
        for (int off = 32; off > 0; off >>= 1) num += __shfl_down(num, off, 64);
        if (l == 0) ws[NUMOFF + grp * CB + b] = num;
    }

    // phase-1 ranges: grp0 fwd [1,64]; grp1..6 bwd [64g+1, 64g+64];
    // grp7 bwd [449,511]
    const int lo1 = (grp == 0) ? 1 : (64 * grp + 1);
    const int hi1 = (grp == 7) ? 511 : (64 * grp + 64);
    const int slot1 = (grp == 0) ? 0 : (6 + grp);
    float* const out1 = ws + 64 + (size_t)slot1 * CB * CK + (size_t)b * CK;

    if (grp == 0) {
        FWD_RUN(1, 64, emB[sj], out1)
    } else {
        BWD_RUN(lo1, hi1, out1)
    }

    if (grp <= 5) {
        // phase 2: direction probe FA_{grp+2} over last 3 steps before
        // boundary b_{grp+2} = 64*(grp+2).
        const int phi = 64 * (grp + 2);
        const int plo = phi - 2;
        float* const out2 = ws + 64 + (size_t)(grp + 1) * CB * CK + (size_t)b * CK;
        __syncthreads();   // order phase-1 LDS reads before phase-2 writes
        FWD_RUN(plo, phi, 0.f, out2)
    }
}

__device__ inline float block_lse(float v, float* red, int tid) {
    const int wid = tid >> 6, lane = tid & 63;
    float mx = v;
    #pragma unroll
    for (int off = 32; off > 0; off >>= 1) mx = fmaxf(mx, __shfl_down(mx, off, 64));
    mx = __shfl(mx, 0, 64);
    if (lane == 0) red[wid] = mx;
    __syncthreads();
    const float g = fmaxf(fmaxf(red[0], red[1]), fmaxf(red[2], red[3]));
    float ex = __expf(v - g);
    #pragma unroll
    for (int off = 32; off > 0; off >>= 1) ex += __shfl_down(ex, off, 64);
    if (lane == 0) red[4 + wid] = ex;
    __syncthreads();
    const float r = g + __logf(red[4] + red[5] + red[6] + red[7]);
    __syncthreads();
    return r;
}

// Telescoped logZ:
// logZ = LSE(FA1+FB1) + sum_{k=2..7} [LSE(FA_k+FB_k) - LSE(FA_k)]
// Numerator: sum of 8 precomputed partials.
__global__ void crf_combine_kernel(float* __restrict__ ws) {
    const int b = blockIdx.x;
    const int tid = threadIdx.x;                 // 256 threads
    __shared__ float red[8];

    if (tid == 0) {
        float num = 0.f;
        #pragma unroll
        for (int g = 0; g < 8; ++g) num += ws[NUMOFF + g * CB + b];
        ws[CB + b] = num;
    }

    const float* base = ws + 64;
    float r;
    {
        const float FA1 = base[0 * CB * CK + b * CK + tid];
        const float FB1 = base[7 * CB * CK + b * CK + tid];
        r = block_lse(FA1 + FB1, red, tid);
    }
    #pragma unroll
    for (int k = 2; k <= 7; ++k) {
        const float FAk = base[(size_t)(k - 1) * CB * CK + b * CK + tid];
        const float FBk = base[(size_t)(6 + k) * CB * CK + b * CK + tid];
        r += block_lse(FAk + FBk, red, tid);
        r -= block_lse(FAk, red, tid);
    }
    if (tid == 0) ws[b] = r;
}

__global__ void crf_finalize_kernel(const float* __restrict__ ws,
                                    float* __restrict__ out) {
    float v = 0.f;
    if ((int)threadIdx.x < CB) v = ws[threadIdx.x] - ws[CB + threadIdx.x];
    #pragma unroll
    for (int off = 32; off > 0; off >>= 1) v += __shfl_down(v, off, 64);
    if (threadIdx.x == 0) out[0] = v * (1.f / CB);
}

extern "C" void kernel_launch(void* const* d_in, const int* in_sizes, int n_in,
                              void* d_out, int out_size, void* d_ws, size_t ws_size,
                              hipStream_t stream) {
    const float* emissions = (const float*)d_in[0];
    const int* tags = (const int*)d_in[1];
    const int* mask = (const int*)d_in[2];
    const float* trans = (const float*)d_in[3];
    float* out = (float*)d_out;
    float* ws = (float*)d_ws;

    crf_seg_kernel<<<8 * CB, 512, 0, stream>>>(emissions, tags, mask, trans, ws);
    crf_combine_kernel<<<CB, 256, 0, stream>>>(ws);
    crf_finalize_kernel<<<1, 64, 0, stream>>>(ws, out);
}